// Round 6
// baseline (293.117 us; speedup 1.0000x reference)
//
#include <hip/hip_runtime.h>

// ---------------------------------------------------------------------------
// MultiHeadAttention: B=2, S=2048, E=1024, H=16, D=64, causal. fp32 I/O.
// R6: (1) split-K flash attention (fixed softmax base m=0 makes partials
// additive): 1536 uniform blocks + fp32 partial merge -> 2x wave residency.
// (2) m97-style global_load_lds(16B) staging in both GEMMs (517->874 TF lever).
// ---------------------------------------------------------------------------

typedef __attribute__((ext_vector_type(8))) short short8;
typedef __attribute__((ext_vector_type(4))) float floatx4;

#define NB 2
#define SEQ 2048
#define EMB 1024
#define NH 16
#define HD 64
#define M_ROWS (NB * SEQ)        // 4096
#define N_QKV (3 * EMB)          // 3072
#define SLOT_F 4160              // 64x64 O + 64 l (floats) per partial slot

#define GLL(g, l) __builtin_amdgcn_global_load_lds( \
    (const __attribute__((address_space(1))) void*)(g), \
    (__attribute__((address_space(3))) void*)(l), 16, 0, 0)

static __device__ __forceinline__ unsigned short f2bf(float f) {
    union { float f; unsigned int u; } v; v.f = f;
    unsigned int r = v.u + 0x7FFFu + ((v.u >> 16) & 1u);
    return (unsigned short)(r >> 16);
}

// x fp32 -> bf16 (4 elems / thread)
__global__ void x_to_bf16(const float* __restrict__ in, unsigned short* __restrict__ out, int n4) {
    int i = blockIdx.x * blockDim.x + threadIdx.x;
    if (i >= n4) return;
    float4 v = ((const float4*)in)[i];
    unsigned long long p = (unsigned long long)f2bf(v.x)
        | ((unsigned long long)f2bf(v.y) << 16)
        | ((unsigned long long)f2bf(v.z) << 32)
        | ((unsigned long long)f2bf(v.w) << 48);
    ((unsigned long long*)out)[i] = p;
}

// W[R][C] fp32 -> Wt[C][R] bf16
__global__ void transpose_f32_bf16(const float* __restrict__ in,
                                   unsigned short* __restrict__ out, int R, int C) {
    __shared__ unsigned short tile[32][33];
    int tx = threadIdx.x, ty = threadIdx.y;
    int c0 = blockIdx.x * 32, r0 = blockIdx.y * 32;
    #pragma unroll
    for (int j = 0; j < 4; ++j)
        tile[ty + j * 8][tx] = f2bf(in[(size_t)(r0 + ty + j * 8) * C + c0 + tx]);
    __syncthreads();
    #pragma unroll
    for (int j = 0; j < 4; ++j)
        out[(size_t)(c0 + ty + j * 8) * R + r0 + tx] = tile[tx][ty + j * 8];
}

// ---------------------------------------------------------------------------
// QKV GEMM, m97-style: unpadded 128x32 LDS tiles, global_load_lds 16B staging.
// Q,K -> [B,H,S,D]; V -> [B,H,D,S] (transposed, packed 8B stores).
// ---------------------------------------------------------------------------
__global__ __launch_bounds__(256) void qkv_gemm(
    const unsigned short* __restrict__ A,    // x_bf [4096][1024]
    const unsigned short* __restrict__ Bt,   // W_qkv^T [3072][1024] bf16
    const float* __restrict__ bias,          // [3072] fp32
    unsigned short* __restrict__ qb, unsigned short* __restrict__ kb,
    unsigned short* __restrict__ vb)         // vb: [B,H,D,S]
{
    const int K = EMB;
    __shared__ __align__(16) unsigned short As[128 * 32];
    __shared__ __align__(16) unsigned short Bs[128 * 32];
    int t = threadIdx.x;
    int m0 = blockIdx.y * 128;
    int n0 = blockIdx.x * 128;
    int w = t >> 6, lane = t & 63, quad = lane >> 4, lcol = lane & 15;
    int wr = w >> 1, wc = w & 1;

    floatx4 zero = {0.f, 0.f, 0.f, 0.f};
    floatx4 acc[4][4];
    #pragma unroll
    for (int i = 0; i < 4; ++i)
        #pragma unroll
        for (int j = 0; j < 4; ++j) acc[i][j] = zero;

    // staging: thread t owns 16B at LDS byte offset t*16 (wave-uniform + lane*16)
    const unsigned short* a0 = A  + (size_t)(m0 + (t >> 2)) * K + ((t & 3) << 3);
    const unsigned short* b0 = Bt + (size_t)(n0 + (t >> 2)) * K + ((t & 3) << 3);
    unsigned short* la = &As[t << 3];        // t*8 shorts = t*16 bytes
    unsigned short* lb = &Bs[t << 3];

    for (int k0 = 0; k0 < K; k0 += 32) {
        __syncthreads();                      // prev compute done
        GLL(a0 + k0, la);
        GLL(a0 + 64 * K + k0, la + 2048);
        GLL(b0 + k0, lb);
        GLL(b0 + 64 * K + k0, lb + 2048);
        __syncthreads();                      // vmcnt(0) drain + barrier (m97)
        short8 af[4], bfm[4];
        #pragma unroll
        for (int i = 0; i < 4; ++i)
            af[i] = *(const short8*)(&As[(wr * 64 + i * 16 + lcol) * 32 + quad * 8]);
        #pragma unroll
        for (int j = 0; j < 4; ++j)
            bfm[j] = *(const short8*)(&Bs[(wc * 64 + j * 16 + lcol) * 32 + quad * 8]);
        #pragma unroll
        for (int i = 0; i < 4; ++i)
            #pragma unroll
            for (int j = 0; j < 4; ++j)
                acc[i][j] = __builtin_amdgcn_mfma_f32_16x16x32_bf16(af[i], bfm[j], acc[i][j], 0, 0, 0);
    }

    #pragma unroll
    for (int i = 0; i < 4; ++i) {
        int m = m0 + wr * 64 + i * 16 + quad * 4;
        int b = m >> 11, s = m & 2047;
        #pragma unroll
        for (int j = 0; j < 4; ++j) {
            int n = n0 + wc * 64 + j * 16 + lcol;
            int which = n >> 10;
            int e = n & 1023;
            int h = e >> 6, d = e & 63;
            float bv = bias[n];
            if (which == 2) {
                size_t base = ((size_t)((b * NH + h) * HD + d)) * SEQ + s;
                unsigned long long pk = (unsigned long long)f2bf(acc[i][j][0] + bv)
                    | ((unsigned long long)f2bf(acc[i][j][1] + bv) << 16)
                    | ((unsigned long long)f2bf(acc[i][j][2] + bv) << 32)
                    | ((unsigned long long)f2bf(acc[i][j][3] + bv) << 48);
                *(unsigned long long*)(&vb[base]) = pk;
            } else {
                unsigned short* dst = (which == 0) ? qb : kb;
                size_t base = ((size_t)((b * NH + h) * SEQ + s)) * HD + d;
                #pragma unroll
                for (int r = 0; r < 4; ++r)
                    dst[base + (size_t)r * HD] = f2bf(acc[i][j][r] + bv);
            }
        }
    }
}

// ---------------------------------------------------------------------------
// Split-K flash attention, causal, fixed softmax base. Block (u, bh):
//   u<16:  qt=u, keys [0, qt+1)           -> final bf16 write
//   u>=16: qt=16+(u-16)/2, c=(u-16)&1, keys c0=[0,16) c1=[16,qt+1)
//          -> fp32 partial (O, l) slot; merged by attn_combine.
// 4 waves x 16 q-rows; one barrier per K-tile; post-barrier prefetch.
// ---------------------------------------------------------------------------
#define KST 72
#define PST 68

__global__ __launch_bounds__(256, 3) void attn_partial(
    const unsigned short* __restrict__ Q,   // [B*H][S][D]
    const unsigned short* __restrict__ Kk,  // [B*H][S][D]
    const unsigned short* __restrict__ Vt,  // [B*H][D][S]
    unsigned short* __restrict__ Out,       // [b][s][h*64+d]
    float* __restrict__ Part)               // partial slots
{
    __shared__ __align__(16) unsigned short Ks[2][64 * KST];
    __shared__ __align__(16) unsigned short Vs[2][64 * KST];
    __shared__ __align__(16) unsigned short Ps[4][16 * PST];

    int u = blockIdx.x;              // 0..47
    int bh = blockIdx.y;
    int qt, c;
    if (u < 16) { qt = u; c = 0; }
    else { int v = u - 16; qt = 16 + (v >> 1); c = v & 1; }
    int ktBeg = c << 4;
    int ktEnd = (c == 0 && qt >= 16) ? 16 : (qt + 1);

    int q0 = qt * 64;
    int t = threadIdx.x;
    int w = t >> 6, lane = t & 63, quad = lane >> 4, lcol = lane & 15;
    const size_t hoff = (size_t)bh * SEQ * HD;
    const float SC = 0.18033688011112043f;   // (1/sqrt(64)) * log2(e)

    const unsigned short* qp = Q + hoff + (size_t)(q0 + 16 * w + lcol) * HD + quad * 8;
    short8 aq0 = *(const short8*)qp, aq1 = *(const short8*)(qp + 32);

    int srow = t >> 2;
    int sseg = (t & 3) << 4;
    const unsigned short* kgl = Kk + hoff + (size_t)srow * HD + sseg;   // + kt*64*HD
    const unsigned short* vgl = Vt + hoff + (size_t)srow * SEQ + sseg;  // + kt*64
    unsigned short* ksw = &Ks[0][srow * KST + sseg];
    unsigned short* vsw = &Vs[0][srow * KST + sseg];
    const int bufStride = 64 * KST;

    floatx4 zero = {0.f, 0.f, 0.f, 0.f};
    floatx4 O[4];
    float l[4];
    #pragma unroll
    for (int r = 0; r < 4; ++r) l[r] = 0.f;
    #pragma unroll
    for (int d = 0; d < 4; ++d) O[d] = zero;

    int4 kv[2][4];
    {
        const unsigned short* kg = kgl + (size_t)ktBeg * 64 * HD;
        const unsigned short* vg = vgl + ktBeg * 64;
        kv[ktBeg & 1][0] = *(const int4*)(kg);
        kv[ktBeg & 1][1] = *(const int4*)(kg + 8);
        kv[ktBeg & 1][2] = *(const int4*)(vg);
        kv[ktBeg & 1][3] = *(const int4*)(vg + 8);
    }

    for (int kt = ktBeg; kt < ktEnd; ++kt) {
        int cur = kt & 1, nxt = cur ^ 1;
        *(int4*)(ksw + cur * bufStride)     = kv[cur][0];
        *(int4*)(ksw + cur * bufStride + 8) = kv[cur][1];
        *(int4*)(vsw + cur * bufStride)     = kv[cur][2];
        *(int4*)(vsw + cur * bufStride + 8) = kv[cur][3];
        __syncthreads();
        if (kt + 1 < ktEnd) {
            const unsigned short* kg = kgl + (size_t)(kt + 1) * 64 * HD;
            const unsigned short* vg = vgl + (kt + 1) * 64;
            kv[nxt][0] = *(const int4*)(kg);
            kv[nxt][1] = *(const int4*)(kg + 8);
            kv[nxt][2] = *(const int4*)(vg);
            kv[nxt][3] = *(const int4*)(vg + 8);
        }

        const unsigned short* ksr = &Ks[cur][0];
        const unsigned short* vsr = &Vs[cur][0];
        short8 bk0[4], bk1[4], bv0[4], bv1[4];
        #pragma unroll
        for (int tc = 0; tc < 4; ++tc) {
            bk0[tc] = *(const short8*)(ksr + (tc * 16 + lcol) * KST + quad * 8);
            bk1[tc] = *(const short8*)(ksr + (tc * 16 + lcol) * KST + 32 + quad * 8);
            bv0[tc] = *(const short8*)(vsr + (tc * 16 + lcol) * KST + quad * 8);
            bv1[tc] = *(const short8*)(vsr + (tc * 16 + lcol) * KST + 32 + quad * 8);
        }

        floatx4 sacc[4];
        #pragma unroll
        for (int tc = 0; tc < 4; ++tc) {
            sacc[tc] = __builtin_amdgcn_mfma_f32_16x16x32_bf16(aq0, bk0[tc], zero, 0, 0, 0);
            sacc[tc] = __builtin_amdgcn_mfma_f32_16x16x32_bf16(aq1, bk1[tc], sacc[tc], 0, 0, 0);
        }
        bool diag = (kt == qt);
        unsigned short* PsW = &Ps[w][0];
        int rbase = 16 * w + quad * 4;
        #pragma unroll
        for (int tc = 0; tc < 4; ++tc) {
            int keyc = tc * 16 + lcol;
            #pragma unroll
            for (int r = 0; r < 4; ++r) {
                float p = __builtin_amdgcn_exp2f(sacc[tc][r] * SC);
                if (diag && keyc > rbase + r) p = 0.f;
                l[r] += p;
                PsW[(quad * 4 + r) * PST + keyc] = f2bf(p);
            }
        }
        short8 ap0 = *(const short8*)(&PsW[lcol * PST + quad * 8]);
        short8 ap1 = *(const short8*)(&PsW[lcol * PST + 32 + quad * 8]);
        #pragma unroll
        for (int td = 0; td < 4; ++td) {
            O[td] = __builtin_amdgcn_mfma_f32_16x16x32_bf16(ap0, bv0[td], O[td], 0, 0, 0);
            O[td] = __builtin_amdgcn_mfma_f32_16x16x32_bf16(ap1, bv1[td], O[td], 0, 0, 0);
        }
    }

    // reduce l across the 16 lanes of each quad-row group
    #pragma unroll
    for (int r = 0; r < 4; ++r) {
        #pragma unroll
        for (int off = 1; off < 16; off <<= 1)
            l[r] += __shfl_xor(l[r], off, 64);
    }

    if (qt < 16) {
        int b = bh >> 4, h = bh & 15;
        size_t obase = ((size_t)b * SEQ) * EMB + (size_t)h * HD;
        #pragma unroll
        for (int td = 0; td < 4; ++td) {
            #pragma unroll
            for (int r = 0; r < 4; ++r) {
                int row = q0 + 16 * w + quad * 4 + r;
                Out[obase + (size_t)row * EMB + td * 16 + lcol] = f2bf(O[td][r] / l[r]);
            }
        }
    } else {
        float* slot = Part + ((size_t)(bh * 16 + (qt - 16)) * 2 + c) * SLOT_F;
        #pragma unroll
        for (int td = 0; td < 4; ++td) {
            #pragma unroll
            for (int r = 0; r < 4; ++r)
                slot[(16 * w + quad * 4 + r) * 64 + td * 16 + lcol] = O[td][r];
        }
        if (lcol == 0) {
            #pragma unroll
            for (int r = 0; r < 4; ++r)
                slot[4096 + 16 * w + quad * 4 + r] = l[r];
        }
    }
}

// merge the 2 partials per (bh, qt>=16) and write bf16 attn rows
__global__ __launch_bounds__(256) void attn_combine(
    const float* __restrict__ Part, unsigned short* __restrict__ Out)
{
    int qh = blockIdx.x;             // 0..15
    int bh = blockIdx.y;
    int qt = 16 + qh;
    const float* s0 = Part + ((size_t)(bh * 16 + qh) * 2) * SLOT_F;
    const float* s1 = s0 + SLOT_F;
    int b = bh >> 4, h = bh & 15;
    size_t obase = ((size_t)b * SEQ + qt * 64) * EMB + (size_t)h * HD;
    int t = threadIdx.x;
    #pragma unroll
    for (int it = 0; it < 16; ++it) {
        int idx = it * 256 + t;
        int row = idx >> 6, col = idx & 63;
        float lv = s0[4096 + row] + s1[4096 + row];
        float v = (s0[idx] + s1[idx]) / lv;
        Out[obase + (size_t)row * EMB + col] = f2bf(v);
    }
}

// ---------------------------------------------------------------------------
// Output projection, m97-style staging. fp32 bias, fp32 out.
// ---------------------------------------------------------------------------
__global__ __launch_bounds__(256) void oproj_gemm(
    const unsigned short* __restrict__ A,    // [4096][1024] bf16
    const unsigned short* __restrict__ Bt,   // W_o^T [1024][1024] bf16
    const float* __restrict__ bias,          // [1024] fp32
    float* __restrict__ Cout)                // [4096][1024] fp32
{
    const int K = EMB;
    __shared__ __align__(16) unsigned short As[128 * 32];
    __shared__ __align__(16) unsigned short Bs[128 * 32];
    int t = threadIdx.x;
    int m0 = blockIdx.y * 128;
    int n0 = blockIdx.x * 128;
    int w = t >> 6, lane = t & 63, quad = lane >> 4, lcol = lane & 15;
    int wr = w >> 1, wc = w & 1;

    floatx4 zero = {0.f, 0.f, 0.f, 0.f};
    floatx4 acc[4][4];
    #pragma unroll
    for (int i = 0; i < 4; ++i)
        #pragma unroll
        for (int j = 0; j < 4; ++j) acc[i][j] = zero;

    const unsigned short* a0 = A  + (size_t)(m0 + (t >> 2)) * K + ((t & 3) << 3);
    const unsigned short* b0 = Bt + (size_t)(n0 + (t >> 2)) * K + ((t & 3) << 3);
    unsigned short* la = &As[t << 3];
    unsigned short* lb = &Bs[t << 3];

    for (int k0 = 0; k0 < K; k0 += 32) {
        __syncthreads();
        GLL(a0 + k0, la);
        GLL(a0 + 64 * K + k0, la + 2048);
        GLL(b0 + k0, lb);
        GLL(b0 + 64 * K + k0, lb + 2048);
        __syncthreads();
        short8 af[4], bfm[4];
        #pragma unroll
        for (int i = 0; i < 4; ++i)
            af[i] = *(const short8*)(&As[(wr * 64 + i * 16 + lcol) * 32 + quad * 8]);
        #pragma unroll
        for (int j = 0; j < 4; ++j)
            bfm[j] = *(const short8*)(&Bs[(wc * 64 + j * 16 + lcol) * 32 + quad * 8]);
        #pragma unroll
        for (int i = 0; i < 4; ++i)
            #pragma unroll
            for (int j = 0; j < 4; ++j)
                acc[i][j] = __builtin_amdgcn_mfma_f32_16x16x32_bf16(af[i], bfm[j], acc[i][j], 0, 0, 0);
    }

    #pragma unroll
    for (int i = 0; i < 4; ++i) {
        int m = m0 + wr * 64 + i * 16 + quad * 4;
        #pragma unroll
        for (int j = 0; j < 4; ++j) {
            int n = n0 + wc * 64 + j * 16 + lcol;
            float bv = bias[n];
            #pragma unroll
            for (int r = 0; r < 4; ++r)
                Cout[(size_t)(m + r) * EMB + n] = acc[i][j][r] + bv;
        }
    }
}

// ---------------------------------------------------------------------------
extern "C" void kernel_launch(void* const* d_in, const int* in_sizes, int n_in,
                              void* d_out, int out_size, void* d_ws, size_t ws_size,
                              hipStream_t stream) {
    (void)in_sizes; (void)n_in; (void)out_size; (void)ws_size;
    char* ws = (char*)d_ws;
    const size_t OFF_X     = 0;                                      // 8 MB
    const size_t OFF_WQKVT = OFF_X     + (size_t)M_ROWS * EMB * 2;   // 6 MB
    const size_t OFF_WOT   = OFF_WQKVT + (size_t)N_QKV * EMB * 2;    // 2 MB
    const size_t OFF_Q     = OFF_WOT   + (size_t)EMB * EMB * 2;      // 8 MB
    const size_t OFF_K     = OFF_Q     + (size_t)M_ROWS * EMB * 2;   // 8 MB
    const size_t OFF_V     = OFF_K     + (size_t)M_ROWS * EMB * 2;   // 8 MB
    const size_t OFF_ATTN  = OFF_V     + (size_t)M_ROWS * EMB * 2;   // 8 MB
    const size_t OFF_PART  = OFF_ATTN  + (size_t)M_ROWS * EMB * 2;   // 17 MB

    const float* x    = (const float*)d_in[0];
    const float* Wqkv = (const float*)d_in[1];
    const float* bqkv = (const float*)d_in[2];
    const float* Wo   = (const float*)d_in[3];
    const float* bo   = (const float*)d_in[4];

    unsigned short* x_bf  = (unsigned short*)(ws + OFF_X);
    unsigned short* wqkvT = (unsigned short*)(ws + OFF_WQKVT);
    unsigned short* woT   = (unsigned short*)(ws + OFF_WOT);
    unsigned short* qb    = (unsigned short*)(ws + OFF_Q);
    unsigned short* kb    = (unsigned short*)(ws + OFF_K);
    unsigned short* vb    = (unsigned short*)(ws + OFF_V);    // [B,H,D,S]
    unsigned short* attn  = (unsigned short*)(ws + OFF_ATTN);
    float*          part  = (float*)(ws + OFF_PART);

    x_to_bf16<<<(M_ROWS * EMB / 4 + 255) / 256, 256, 0, stream>>>(x, x_bf, M_ROWS * EMB / 4);
    transpose_f32_bf16<<<dim3(N_QKV / 32, EMB / 32), dim3(32, 8), 0, stream>>>(Wqkv, wqkvT, EMB, N_QKV);
    transpose_f32_bf16<<<dim3(EMB / 32, EMB / 32), dim3(32, 8), 0, stream>>>(Wo, woT, EMB, EMB);

    qkv_gemm<<<dim3(N_QKV / 128, M_ROWS / 128), 256, 0, stream>>>(x_bf, wqkvT, bqkv, qb, kb, vb);
    attn_partial<<<dim3(48, NB * NH), 256, 0, stream>>>(qb, kb, vb, attn, part);
    attn_combine<<<dim3(16, NB * NH), 256, 0, stream>>>(part, attn);
    oproj_gemm<<<dim3(EMB / 128, M_ROWS / 128), 256, 0, stream>>>(attn, woT, bo, (float*)d_out);
}

// Round 7
// 241.939 us; speedup vs baseline: 1.2115x; 1.2115x over previous
//
#include <hip/hip_runtime.h>

// ---------------------------------------------------------------------------
// MultiHeadAttention: B=2, S=2048, E=1024, H=16, D=64, causal. fp32 I/O.
// R7: split-K flash attention (R6) with the spill fixed:
//  - no min-wave launch_bounds (R6's (256,3) forced VGPR=68 -> scratch spills,
//    264MB WRITE_SIZE). Occupancy now LDS-bound: 3 blocks/CU.
//  - K/V staged via global_load_lds(16B) with XOR-swizzled segments
//    (LDS[r][s] = G[r][s^(r&7)]) -> unpadded 64x64 tiles, conflict-free
//    b128 frag reads, no VALU staging, no prefetch registers.
// GEMMs: m97-style GLL staging (unchanged from R6).
// ---------------------------------------------------------------------------

typedef __attribute__((ext_vector_type(8))) short short8;
typedef __attribute__((ext_vector_type(4))) float floatx4;

#define NB 2
#define SEQ 2048
#define EMB 1024
#define NH 16
#define HD 64
#define M_ROWS (NB * SEQ)        // 4096
#define N_QKV (3 * EMB)          // 3072
#define SLOT_F 4160              // 64x64 O + 64 l (floats) per partial slot

#define GLL(g, l) __builtin_amdgcn_global_load_lds( \
    (const __attribute__((address_space(1))) void*)(g), \
    (__attribute__((address_space(3))) void*)(l), 16, 0, 0)

static __device__ __forceinline__ unsigned short f2bf(float f) {
    union { float f; unsigned int u; } v; v.f = f;
    unsigned int r = v.u + 0x7FFFu + ((v.u >> 16) & 1u);
    return (unsigned short)(r >> 16);
}

// x fp32 -> bf16 (4 elems / thread)
__global__ void x_to_bf16(const float* __restrict__ in, unsigned short* __restrict__ out, int n4) {
    int i = blockIdx.x * blockDim.x + threadIdx.x;
    if (i >= n4) return;
    float4 v = ((const float4*)in)[i];
    unsigned long long p = (unsigned long long)f2bf(v.x)
        | ((unsigned long long)f2bf(v.y) << 16)
        | ((unsigned long long)f2bf(v.z) << 32)
        | ((unsigned long long)f2bf(v.w) << 48);
    ((unsigned long long*)out)[i] = p;
}

// W[R][C] fp32 -> Wt[C][R] bf16
__global__ void transpose_f32_bf16(const float* __restrict__ in,
                                   unsigned short* __restrict__ out, int R, int C) {
    __shared__ unsigned short tile[32][33];
    int tx = threadIdx.x, ty = threadIdx.y;
    int c0 = blockIdx.x * 32, r0 = blockIdx.y * 32;
    #pragma unroll
    for (int j = 0; j < 4; ++j)
        tile[ty + j * 8][tx] = f2bf(in[(size_t)(r0 + ty + j * 8) * C + c0 + tx]);
    __syncthreads();
    #pragma unroll
    for (int j = 0; j < 4; ++j)
        out[(size_t)(c0 + ty + j * 8) * R + r0 + tx] = tile[tx][ty + j * 8];
}

// ---------------------------------------------------------------------------
// QKV GEMM, m97-style: unpadded 128x32 LDS tiles, global_load_lds 16B staging.
// Q,K -> [B,H,S,D]; V -> [B,H,D,S] (transposed, packed 8B stores).
// ---------------------------------------------------------------------------
__global__ __launch_bounds__(256) void qkv_gemm(
    const unsigned short* __restrict__ A,    // x_bf [4096][1024]
    const unsigned short* __restrict__ Bt,   // W_qkv^T [3072][1024] bf16
    const float* __restrict__ bias,          // [3072] fp32
    unsigned short* __restrict__ qb, unsigned short* __restrict__ kb,
    unsigned short* __restrict__ vb)         // vb: [B,H,D,S]
{
    const int K = EMB;
    __shared__ __align__(16) unsigned short As[128 * 32];
    __shared__ __align__(16) unsigned short Bs[128 * 32];
    int t = threadIdx.x;
    int m0 = blockIdx.y * 128;
    int n0 = blockIdx.x * 128;
    int w = t >> 6, lane = t & 63, quad = lane >> 4, lcol = lane & 15;
    int wr = w >> 1, wc = w & 1;

    floatx4 zero = {0.f, 0.f, 0.f, 0.f};
    floatx4 acc[4][4];
    #pragma unroll
    for (int i = 0; i < 4; ++i)
        #pragma unroll
        for (int j = 0; j < 4; ++j) acc[i][j] = zero;

    const unsigned short* a0 = A  + (size_t)(m0 + (t >> 2)) * K + ((t & 3) << 3);
    const unsigned short* b0 = Bt + (size_t)(n0 + (t >> 2)) * K + ((t & 3) << 3);
    unsigned short* la = &As[t << 3];        // t*8 shorts = t*16 bytes
    unsigned short* lb = &Bs[t << 3];

    for (int k0 = 0; k0 < K; k0 += 32) {
        __syncthreads();                      // prev compute done
        GLL(a0 + k0, la);
        GLL(a0 + 64 * K + k0, la + 2048);
        GLL(b0 + k0, lb);
        GLL(b0 + 64 * K + k0, lb + 2048);
        __syncthreads();                      // vmcnt(0) drain + barrier (m97)
        short8 af[4], bfm[4];
        #pragma unroll
        for (int i = 0; i < 4; ++i)
            af[i] = *(const short8*)(&As[(wr * 64 + i * 16 + lcol) * 32 + quad * 8]);
        #pragma unroll
        for (int j = 0; j < 4; ++j)
            bfm[j] = *(const short8*)(&Bs[(wc * 64 + j * 16 + lcol) * 32 + quad * 8]);
        #pragma unroll
        for (int i = 0; i < 4; ++i)
            #pragma unroll
            for (int j = 0; j < 4; ++j)
                acc[i][j] = __builtin_amdgcn_mfma_f32_16x16x32_bf16(af[i], bfm[j], acc[i][j], 0, 0, 0);
    }

    #pragma unroll
    for (int i = 0; i < 4; ++i) {
        int m = m0 + wr * 64 + i * 16 + quad * 4;
        int b = m >> 11, s = m & 2047;
        #pragma unroll
        for (int j = 0; j < 4; ++j) {
            int n = n0 + wc * 64 + j * 16 + lcol;
            int which = n >> 10;
            int e = n & 1023;
            int h = e >> 6, d = e & 63;
            float bv = bias[n];
            if (which == 2) {
                size_t base = ((size_t)((b * NH + h) * HD + d)) * SEQ + s;
                unsigned long long pk = (unsigned long long)f2bf(acc[i][j][0] + bv)
                    | ((unsigned long long)f2bf(acc[i][j][1] + bv) << 16)
                    | ((unsigned long long)f2bf(acc[i][j][2] + bv) << 32)
                    | ((unsigned long long)f2bf(acc[i][j][3] + bv) << 48);
                *(unsigned long long*)(&vb[base]) = pk;
            } else {
                unsigned short* dst = (which == 0) ? qb : kb;
                size_t base = ((size_t)((b * NH + h) * SEQ + s)) * HD + d;
                #pragma unroll
                for (int r = 0; r < 4; ++r)
                    dst[base + (size_t)r * HD] = f2bf(acc[i][j][r] + bv);
            }
        }
    }
}

// ---------------------------------------------------------------------------
// Split-K flash attention, causal, fixed softmax base. Block (u, bh):
//   u<16:  qt=u, keys [0, qt+1)           -> final bf16 write
//   u>=16: qt=16+(u-16)/2, c=(u-16)&1, keys c0=[0,16) c1=[16,qt+1)
//          -> fp32 partial (O, l) slot; merged by attn_combine.
// GLL staging, XOR-swizzled segs; one barrier per K-tile; post-barrier prefetch.
// ---------------------------------------------------------------------------
#define PST 68

__global__ __launch_bounds__(256) void attn_partial(
    const unsigned short* __restrict__ Q,   // [B*H][S][D]
    const unsigned short* __restrict__ Kk,  // [B*H][S][D]
    const unsigned short* __restrict__ Vt,  // [B*H][D][S]
    unsigned short* __restrict__ Out,       // [b][s][h*64+d]
    float* __restrict__ Part)               // partial slots
{
    __shared__ __align__(16) unsigned short Ks[2][64 * 64];
    __shared__ __align__(16) unsigned short Vs[2][64 * 64];
    __shared__ __align__(16) unsigned short Ps[4][16 * PST];

    int u = blockIdx.x;              // 0..47
    int bh = blockIdx.y;
    int qt, c;
    if (u < 16) { qt = u; c = 0; }
    else { int v = u - 16; qt = 16 + (v >> 1); c = v & 1; }
    int ktBeg = c << 4;
    int ktEnd = (c == 0 && qt >= 16) ? 16 : (qt + 1);

    int q0 = qt * 64;
    int t = threadIdx.x;
    int w = t >> 6, lane = t & 63, quad = lane >> 4, lcol = lane & 15;
    const size_t hoff = (size_t)bh * SEQ * HD;
    const float SC = 0.18033688011112043f;   // (1/sqrt(64)) * log2(e)

    const unsigned short* qp = Q + hoff + (size_t)(q0 + 16 * w + lcol) * HD + quad * 8;
    short8 aq0 = *(const short8*)qp, aq1 = *(const short8*)(qp + 32);

    // GLL staging: thread t stages rows r=(t>>3)+32j, dest seg sd=t&7,
    // source seg ss = sd ^ (r&7)  =>  LDS[r][sd] = Global[r][sd^(r&7)].
    int srow = t >> 3;                       // 0..31
    int ss   = (t & 7) ^ (srow & 7);
    const unsigned short* kgl = Kk + hoff + (size_t)srow * HD + ss * 8;   // + (k0+32j)*HD
    const unsigned short* vgl = Vt + hoff + (size_t)srow * SEQ + ss * 8;  // + 32j*SEQ + k0
    unsigned short* kld = &Ks[0][t * 8];     // + nxt*4096 + j*2048 (shorts)
    unsigned short* vld = &Vs[0][t * 8];

    floatx4 zero = {0.f, 0.f, 0.f, 0.f};
    floatx4 O[4];
    float l[4] = {0.f, 0.f, 0.f, 0.f};
    #pragma unroll
    for (int d = 0; d < 4; ++d) O[d] = zero;

    {   // prologue: stage tile ktBeg into buf 0 (ktBeg is even)
        int k0 = ktBeg * 64;
        GLL(kgl + (size_t)k0 * HD, kld);
        GLL(kgl + (size_t)(k0 + 32) * HD, kld + 2048);
        GLL(vgl + k0, vld);
        GLL(vgl + (size_t)32 * SEQ + k0, vld + 2048);
    }

    int sx0 = (quad ^ (lcol & 7)) << 3;      // LDS seg offset (shorts) for g=quad
    int sx1 = sx0 ^ 32;                      // for g=quad+4

    for (int kt = ktBeg; kt < ktEnd; ++kt) {
        int cur = kt & 1, nxt = cur ^ 1;
        __syncthreads();                     // drains tile-kt staging loads
        if (kt + 1 < ktEnd) {
            int k0 = (kt + 1) * 64;
            GLL(kgl + (size_t)k0 * HD, kld + nxt * 4096);
            GLL(kgl + (size_t)(k0 + 32) * HD, kld + nxt * 4096 + 2048);
            GLL(vgl + k0, vld + nxt * 4096);
            GLL(vgl + (size_t)32 * SEQ + k0, vld + nxt * 4096 + 2048);
        }

        const unsigned short* ksr = &Ks[cur][0];
        const unsigned short* vsr = &Vs[cur][0];
        short8 bk0[4], bk1[4], bv0[4], bv1[4];
        #pragma unroll
        for (int tc = 0; tc < 4; ++tc) {
            int rb = (tc * 16 + lcol) << 6;
            bk0[tc] = *(const short8*)(ksr + rb + sx0);
            bk1[tc] = *(const short8*)(ksr + rb + sx1);
            bv0[tc] = *(const short8*)(vsr + rb + sx0);
            bv1[tc] = *(const short8*)(vsr + rb + sx1);
        }

        floatx4 sacc[4];
        #pragma unroll
        for (int tc = 0; tc < 4; ++tc) {
            sacc[tc] = __builtin_amdgcn_mfma_f32_16x16x32_bf16(aq0, bk0[tc], zero, 0, 0, 0);
            sacc[tc] = __builtin_amdgcn_mfma_f32_16x16x32_bf16(aq1, bk1[tc], sacc[tc], 0, 0, 0);
        }
        bool diag = (kt == qt);
        unsigned short* PsW = &Ps[w][0];
        int rbase = 16 * w + quad * 4;
        #pragma unroll
        for (int tc = 0; tc < 4; ++tc) {
            int keyc = tc * 16 + lcol;
            #pragma unroll
            for (int r = 0; r < 4; ++r) {
                float p = __builtin_amdgcn_exp2f(sacc[tc][r] * SC);
                if (diag && keyc > rbase + r) p = 0.f;
                l[r] += p;
                PsW[(quad * 4 + r) * PST + keyc] = f2bf(p);
            }
        }
        short8 ap0 = *(const short8*)(&PsW[lcol * PST + quad * 8]);
        short8 ap1 = *(const short8*)(&PsW[lcol * PST + 32 + quad * 8]);
        #pragma unroll
        for (int td = 0; td < 4; ++td) {
            O[td] = __builtin_amdgcn_mfma_f32_16x16x32_bf16(ap0, bv0[td], O[td], 0, 0, 0);
            O[td] = __builtin_amdgcn_mfma_f32_16x16x32_bf16(ap1, bv1[td], O[td], 0, 0, 0);
        }
    }

    // reduce l across the 16 lanes of each quad-row group
    #pragma unroll
    for (int r = 0; r < 4; ++r) {
        #pragma unroll
        for (int off = 1; off < 16; off <<= 1)
            l[r] += __shfl_xor(l[r], off, 64);
    }

    if (qt < 16) {
        int b = bh >> 4, h = bh & 15;
        size_t obase = ((size_t)b * SEQ) * EMB + (size_t)h * HD;
        #pragma unroll
        for (int td = 0; td < 4; ++td) {
            #pragma unroll
            for (int r = 0; r < 4; ++r) {
                int row = q0 + 16 * w + quad * 4 + r;
                Out[obase + (size_t)row * EMB + td * 16 + lcol] = f2bf(O[td][r] / l[r]);
            }
        }
    } else {
        float* slot = Part + ((size_t)(bh * 16 + (qt - 16)) * 2 + c) * SLOT_F;
        #pragma unroll
        for (int td = 0; td < 4; ++td) {
            #pragma unroll
            for (int r = 0; r < 4; ++r)
                slot[(16 * w + quad * 4 + r) * 64 + td * 16 + lcol] = O[td][r];
        }
        if (lcol == 0) {
            #pragma unroll
            for (int r = 0; r < 4; ++r)
                slot[4096 + 16 * w + quad * 4 + r] = l[r];
        }
    }
}

// merge the 2 partials per (bh, qt>=16) and write bf16 attn rows
__global__ __launch_bounds__(256) void attn_combine(
    const float* __restrict__ Part, unsigned short* __restrict__ Out)
{
    int qh = blockIdx.x;             // 0..15
    int bh = blockIdx.y;
    int qt = 16 + qh;
    const float* s0 = Part + ((size_t)(bh * 16 + qh) * 2) * SLOT_F;
    const float* s1 = s0 + SLOT_F;
    int b = bh >> 4, h = bh & 15;
    size_t obase = ((size_t)b * SEQ + qt * 64) * EMB + (size_t)h * HD;
    int t = threadIdx.x;
    #pragma unroll
    for (int it = 0; it < 16; ++it) {
        int idx = it * 256 + t;
        int row = idx >> 6, col = idx & 63;
        float lv = s0[4096 + row] + s1[4096 + row];
        float v = (s0[idx] + s1[idx]) / lv;
        Out[obase + (size_t)row * EMB + col] = f2bf(v);
    }
}

// ---------------------------------------------------------------------------
// Output projection, m97-style staging. fp32 bias, fp32 out.
// ---------------------------------------------------------------------------
__global__ __launch_bounds__(256) void oproj_gemm(
    const unsigned short* __restrict__ A,    // [4096][1024] bf16
    const unsigned short* __restrict__ Bt,   // W_o^T [1024][1024] bf16
    const float* __restrict__ bias,          // [1024] fp32
    float* __restrict__ Cout)                // [4096][1024] fp32
{
    const int K = EMB;
    __shared__ __align__(16) unsigned short As[128 * 32];
    __shared__ __align__(16) unsigned short Bs[128 * 32];
    int t = threadIdx.x;
    int m0 = blockIdx.y * 128;
    int n0 = blockIdx.x * 128;
    int w = t >> 6, lane = t & 63, quad = lane >> 4, lcol = lane & 15;
    int wr = w >> 1, wc = w & 1;

    floatx4 zero = {0.f, 0.f, 0.f, 0.f};
    floatx4 acc[4][4];
    #pragma unroll
    for (int i = 0; i < 4; ++i)
        #pragma unroll
        for (int j = 0; j < 4; ++j) acc[i][j] = zero;

    const unsigned short* a0 = A  + (size_t)(m0 + (t >> 2)) * K + ((t & 3) << 3);
    const unsigned short* b0 = Bt + (size_t)(n0 + (t >> 2)) * K + ((t & 3) << 3);
    unsigned short* la = &As[t << 3];
    unsigned short* lb = &Bs[t << 3];

    for (int k0 = 0; k0 < K; k0 += 32) {
        __syncthreads();
        GLL(a0 + k0, la);
        GLL(a0 + 64 * K + k0, la + 2048);
        GLL(b0 + k0, lb);
        GLL(b0 + 64 * K + k0, lb + 2048);
        __syncthreads();
        short8 af[4], bfm[4];
        #pragma unroll
        for (int i = 0; i < 4; ++i)
            af[i] = *(const short8*)(&As[(wr * 64 + i * 16 + lcol) * 32 + quad * 8]);
        #pragma unroll
        for (int j = 0; j < 4; ++j)
            bfm[j] = *(const short8*)(&Bs[(wc * 64 + j * 16 + lcol) * 32 + quad * 8]);
        #pragma unroll
        for (int i = 0; i < 4; ++i)
            #pragma unroll
            for (int j = 0; j < 4; ++j)
                acc[i][j] = __builtin_amdgcn_mfma_f32_16x16x32_bf16(af[i], bfm[j], acc[i][j], 0, 0, 0);
    }

    #pragma unroll
    for (int i = 0; i < 4; ++i) {
        int m = m0 + wr * 64 + i * 16 + quad * 4;
        #pragma unroll
        for (int j = 0; j < 4; ++j) {
            int n = n0 + wc * 64 + j * 16 + lcol;
            float bv = bias[n];
            #pragma unroll
            for (int r = 0; r < 4; ++r)
                Cout[(size_t)(m + r) * EMB + n] = acc[i][j][r] + bv;
        }
    }
}

// ---------------------------------------------------------------------------
extern "C" void kernel_launch(void* const* d_in, const int* in_sizes, int n_in,
                              void* d_out, int out_size, void* d_ws, size_t ws_size,
                              hipStream_t stream) {
    (void)in_sizes; (void)n_in; (void)out_size; (void)ws_size;
    char* ws = (char*)d_ws;
    const size_t OFF_X     = 0;                                      // 8 MB
    const size_t OFF_WQKVT = OFF_X     + (size_t)M_ROWS * EMB * 2;   // 6 MB
    const size_t OFF_WOT   = OFF_WQKVT + (size_t)N_QKV * EMB * 2;    // 2 MB
    const size_t OFF_Q     = OFF_WOT   + (size_t)EMB * EMB * 2;      // 8 MB
    const size_t OFF_K     = OFF_Q     + (size_t)M_ROWS * EMB * 2;   // 8 MB
    const size_t OFF_V     = OFF_K     + (size_t)M_ROWS * EMB * 2;   // 8 MB
    const size_t OFF_ATTN  = OFF_V     + (size_t)M_ROWS * EMB * 2;   // 8 MB
    const size_t OFF_PART  = OFF_ATTN  + (size_t)M_ROWS * EMB * 2;   // 17 MB

    const float* x    = (const float*)d_in[0];
    const float* Wqkv = (const float*)d_in[1];
    const float* bqkv = (const float*)d_in[2];
    const float* Wo   = (const float*)d_in[3];
    const float* bo   = (const float*)d_in[4];

    unsigned short* x_bf  = (unsigned short*)(ws + OFF_X);
    unsigned short* wqkvT = (unsigned short*)(ws + OFF_WQKVT);
    unsigned short* woT   = (unsigned short*)(ws + OFF_WOT);
    unsigned short* qb    = (unsigned short*)(ws + OFF_Q);
    unsigned short* kb    = (unsigned short*)(ws + OFF_K);
    unsigned short* vb    = (unsigned short*)(ws + OFF_V);    // [B,H,D,S]
    unsigned short* attn  = (unsigned short*)(ws + OFF_ATTN);
    float*          part  = (float*)(ws + OFF_PART);

    x_to_bf16<<<(M_ROWS * EMB / 4 + 255) / 256, 256, 0, stream>>>(x, x_bf, M_ROWS * EMB / 4);
    transpose_f32_bf16<<<dim3(N_QKV / 32, EMB / 32), dim3(32, 8), 0, stream>>>(Wqkv, wqkvT, EMB, N_QKV);
    transpose_f32_bf16<<<dim3(EMB / 32, EMB / 32), dim3(32, 8), 0, stream>>>(Wo, woT, EMB, EMB);

    qkv_gemm<<<dim3(N_QKV / 128, M_ROWS / 128), 256, 0, stream>>>(x_bf, wqkvT, bqkv, qb, kb, vb);
    attn_partial<<<dim3(48, NB * NH), 256, 0, stream>>>(qb, kb, vb, attn, part);
    attn_combine<<<dim3(16, NB * NH), 256, 0, stream>>>(part, attn);
    oproj_gemm<<<dim3(EMB / 128, M_ROWS / 128), 256, 0, stream>>>(attn, woT, bo, (float*)d_out);
}

// Round 8
// 224.573 us; speedup vs baseline: 1.3052x; 1.0773x over previous
//
#include <hip/hip_runtime.h>

// ---------------------------------------------------------------------------
// MultiHeadAttention: B=2, S=2048, E=1024, H=16, D=64, causal. fp32 I/O.
// R8: (1) qkv_gemm epilogue -> LDS-roundtrip coalesced stores (128B segments;
// Q/K token-major, V feature-major). R5-R7 data shows the GEMM block (~130us)
// didn't respond to K-loop upgrades -> scatter-store bound. (2) attn: peel
// causal mask out of non-diagonal iterations (uniform branch).
// ---------------------------------------------------------------------------

typedef __attribute__((ext_vector_type(8))) short short8;
typedef __attribute__((ext_vector_type(4))) float floatx4;

#define NB 2
#define SEQ 2048
#define EMB 1024
#define NH 16
#define HD 64
#define M_ROWS (NB * SEQ)        // 4096
#define N_QKV (3 * EMB)          // 3072
#define SLOT_F 4160              // 64x64 O + 64 l (floats) per partial slot

#define GLL(g, l) __builtin_amdgcn_global_load_lds( \
    (const __attribute__((address_space(1))) void*)(g), \
    (__attribute__((address_space(3))) void*)(l), 16, 0, 0)

static __device__ __forceinline__ unsigned short f2bf(float f) {
    union { float f; unsigned int u; } v; v.f = f;
    unsigned int r = v.u + 0x7FFFu + ((v.u >> 16) & 1u);
    return (unsigned short)(r >> 16);
}

// x fp32 -> bf16 (4 elems / thread)
__global__ void x_to_bf16(const float* __restrict__ in, unsigned short* __restrict__ out, int n4) {
    int i = blockIdx.x * blockDim.x + threadIdx.x;
    if (i >= n4) return;
    float4 v = ((const float4*)in)[i];
    unsigned long long p = (unsigned long long)f2bf(v.x)
        | ((unsigned long long)f2bf(v.y) << 16)
        | ((unsigned long long)f2bf(v.z) << 32)
        | ((unsigned long long)f2bf(v.w) << 48);
    ((unsigned long long*)out)[i] = p;
}

// W[R][C] fp32 -> Wt[C][R] bf16
__global__ void transpose_f32_bf16(const float* __restrict__ in,
                                   unsigned short* __restrict__ out, int R, int C) {
    __shared__ unsigned short tile[32][33];
    int tx = threadIdx.x, ty = threadIdx.y;
    int c0 = blockIdx.x * 32, r0 = blockIdx.y * 32;
    #pragma unroll
    for (int j = 0; j < 4; ++j)
        tile[ty + j * 8][tx] = f2bf(in[(size_t)(r0 + ty + j * 8) * C + c0 + tx]);
    __syncthreads();
    #pragma unroll
    for (int j = 0; j < 4; ++j)
        out[(size_t)(c0 + ty + j * 8) * R + r0 + tx] = tile[tx][ty + j * 8];
}

// ---------------------------------------------------------------------------
// QKV GEMM: GLL staging (m97) + LDS-roundtrip coalesced epilogue.
// Q,K -> [B,H,S,D]; V -> [B,H,D,S]. All stores 16B, 128B segments.
// ---------------------------------------------------------------------------
#define CTS 130   // C-tile LDS stride (shorts), pad 2

__global__ __launch_bounds__(256) void qkv_gemm(
    const unsigned short* __restrict__ A,    // x_bf [4096][1024]
    const unsigned short* __restrict__ Bt,   // W_qkv^T [3072][1024] bf16
    const float* __restrict__ bias,          // [3072] fp32
    unsigned short* __restrict__ qb, unsigned short* __restrict__ kb,
    unsigned short* __restrict__ vb)         // vb: [B,H,D,S]
{
    const int K = EMB;
    // union: staging (As 4096 + Bs 4096 shorts) vs C-tile (128*130 shorts)
    __shared__ __align__(16) unsigned short smem[128 * CTS];
    unsigned short* As = smem;
    unsigned short* Bs = smem + 4096;

    int t = threadIdx.x;
    int m0 = blockIdx.y * 128;
    int n0 = blockIdx.x * 128;
    int w = t >> 6, lane = t & 63, quad = lane >> 4, lcol = lane & 15;
    int wr = w >> 1, wc = w & 1;

    floatx4 zero = {0.f, 0.f, 0.f, 0.f};
    floatx4 acc[4][4];
    #pragma unroll
    for (int i = 0; i < 4; ++i)
        #pragma unroll
        for (int j = 0; j < 4; ++j) acc[i][j] = zero;

    const unsigned short* a0 = A  + (size_t)(m0 + (t >> 2)) * K + ((t & 3) << 3);
    const unsigned short* b0 = Bt + (size_t)(n0 + (t >> 2)) * K + ((t & 3) << 3);
    unsigned short* la = &As[t << 3];
    unsigned short* lb = &Bs[t << 3];

    for (int k0 = 0; k0 < K; k0 += 32) {
        __syncthreads();
        GLL(a0 + k0, la);
        GLL(a0 + 64 * K + k0, la + 2048);
        GLL(b0 + k0, lb);
        GLL(b0 + 64 * K + k0, lb + 2048);
        __syncthreads();
        short8 af[4], bfm[4];
        #pragma unroll
        for (int i = 0; i < 4; ++i)
            af[i] = *(const short8*)(&As[(wr * 64 + i * 16 + lcol) * 32 + quad * 8]);
        #pragma unroll
        for (int j = 0; j < 4; ++j)
            bfm[j] = *(const short8*)(&Bs[(wc * 64 + j * 16 + lcol) * 32 + quad * 8]);
        #pragma unroll
        for (int i = 0; i < 4; ++i)
            #pragma unroll
            for (int j = 0; j < 4; ++j)
                acc[i][j] = __builtin_amdgcn_mfma_f32_16x16x32_bf16(af[i], bfm[j], acc[i][j], 0, 0, 0);
    }

    // ---- epilogue: bias + bf16 into LDS C-tile, then coalesced streams ----
    bool isV = (n0 >= 2 * EMB);
    __syncthreads();                          // staging reads done everywhere
    #pragma unroll
    for (int i = 0; i < 4; ++i) {
        int row0 = wr * 64 + i * 16 + quad * 4;
        #pragma unroll
        for (int j = 0; j < 4; ++j) {
            int col = wc * 64 + j * 16 + lcol;
            float bv = bias[n0 + col];
            #pragma unroll
            for (int r = 0; r < 4; ++r) {
                unsigned short hv = f2bf(acc[i][j][r] + bv);
                if (isV) smem[col * CTS + row0 + r] = hv;   // [feature][token]
                else     smem[(row0 + r) * CTS + col] = hv; // [token][feature]
            }
        }
    }
    __syncthreads();

    int b = m0 >> 11, s0 = m0 & 2047;
    int hbase = (n0 & 1023) >> 6;
    if (!isV) {
        unsigned short* dst = (n0 >= EMB) ? kb : qb;
        #pragma unroll
        for (int it = 0; it < 8; ++it) {
            int job = it * 32 + (t >> 3);    // 0..255
            int tok = job & 127, hh = job >> 7;
            int chunk = t & 7;
            short8 vv = *(const short8*)(&smem[tok * CTS + hh * 64 + chunk * 8]);
            size_t g = ((size_t)((b * NH + hbase + hh) * SEQ + s0 + tok)) * HD + chunk * 8;
            *(short8*)(&dst[g]) = vv;
        }
    } else {
        #pragma unroll
        for (int it = 0; it < 8; ++it) {
            int job = it * 32 + (t >> 3);    // 0..255
            int f = job & 127, half = job >> 7;
            int chunk = (t & 7) + half * 8;  // 0..15 token-chunks of 8
            short8 vv = *(const short8*)(&smem[f * CTS + chunk * 8]);
            int h = hbase + (f >> 6), d = f & 63;
            size_t g = ((size_t)((b * NH + h) * HD + d)) * SEQ + s0 + chunk * 8;
            *(short8*)(&vb[g]) = vv;
        }
    }
}

// ---------------------------------------------------------------------------
// Split-K flash attention, causal, fixed softmax base. Block (u, bh):
//   u<16:  qt=u, keys [0, qt+1)           -> final bf16 write
//   u>=16: qt=16+(u-16)/2, c=(u-16)&1, keys c0=[0,16) c1=[16,qt+1)
// GLL staging, XOR-swizzled segs; diagonal mask peeled to a uniform branch.
// ---------------------------------------------------------------------------
#define PST 68

__global__ __launch_bounds__(256) void attn_partial(
    const unsigned short* __restrict__ Q,   // [B*H][S][D]
    const unsigned short* __restrict__ Kk,  // [B*H][S][D]
    const unsigned short* __restrict__ Vt,  // [B*H][D][S]
    unsigned short* __restrict__ Out,       // [b][s][h*64+d]
    float* __restrict__ Part)               // partial slots
{
    __shared__ __align__(16) unsigned short Ks[2][64 * 64];
    __shared__ __align__(16) unsigned short Vs[2][64 * 64];
    __shared__ __align__(16) unsigned short Ps[4][16 * PST];

    int u = blockIdx.x;              // 0..47
    int bh = blockIdx.y;
    int qt, c;
    if (u < 16) { qt = u; c = 0; }
    else { int v = u - 16; qt = 16 + (v >> 1); c = v & 1; }
    int ktBeg = c << 4;
    int ktEnd = (c == 0 && qt >= 16) ? 16 : (qt + 1);

    int q0 = qt * 64;
    int t = threadIdx.x;
    int w = t >> 6, lane = t & 63, quad = lane >> 4, lcol = lane & 15;
    const size_t hoff = (size_t)bh * SEQ * HD;
    const float SC = 0.18033688011112043f;   // (1/sqrt(64)) * log2(e)

    const unsigned short* qp = Q + hoff + (size_t)(q0 + 16 * w + lcol) * HD + quad * 8;
    short8 aq0 = *(const short8*)qp, aq1 = *(const short8*)(qp + 32);

    int srow = t >> 3;                       // 0..31
    int ss   = (t & 7) ^ (srow & 7);
    const unsigned short* kgl = Kk + hoff + (size_t)srow * HD + ss * 8;
    const unsigned short* vgl = Vt + hoff + (size_t)srow * SEQ + ss * 8;
    unsigned short* kld = &Ks[0][t * 8];
    unsigned short* vld = &Vs[0][t * 8];

    floatx4 zero = {0.f, 0.f, 0.f, 0.f};
    floatx4 O[4];
    float l[4] = {0.f, 0.f, 0.f, 0.f};
    #pragma unroll
    for (int d = 0; d < 4; ++d) O[d] = zero;

    {   // prologue: stage tile ktBeg into buf 0 (ktBeg is even)
        int k0 = ktBeg * 64;
        GLL(kgl + (size_t)k0 * HD, kld);
        GLL(kgl + (size_t)(k0 + 32) * HD, kld + 2048);
        GLL(vgl + k0, vld);
        GLL(vgl + (size_t)32 * SEQ + k0, vld + 2048);
    }

    int sx0 = (quad ^ (lcol & 7)) << 3;
    int sx1 = sx0 ^ 32;

    for (int kt = ktBeg; kt < ktEnd; ++kt) {
        int cur = kt & 1, nxt = cur ^ 1;
        __syncthreads();                     // drains tile-kt staging loads
        if (kt + 1 < ktEnd) {
            int k0 = (kt + 1) * 64;
            GLL(kgl + (size_t)k0 * HD, kld + nxt * 4096);
            GLL(kgl + (size_t)(k0 + 32) * HD, kld + nxt * 4096 + 2048);
            GLL(vgl + k0, vld + nxt * 4096);
            GLL(vgl + (size_t)32 * SEQ + k0, vld + nxt * 4096 + 2048);
        }

        const unsigned short* ksr = &Ks[cur][0];
        const unsigned short* vsr = &Vs[cur][0];
        short8 bk0[4], bk1[4], bv0[4], bv1[4];
        #pragma unroll
        for (int tc = 0; tc < 4; ++tc) {
            int rb = (tc * 16 + lcol) << 6;
            bk0[tc] = *(const short8*)(ksr + rb + sx0);
            bk1[tc] = *(const short8*)(ksr + rb + sx1);
            bv0[tc] = *(const short8*)(vsr + rb + sx0);
            bv1[tc] = *(const short8*)(vsr + rb + sx1);
        }

        floatx4 sacc[4];
        #pragma unroll
        for (int tc = 0; tc < 4; ++tc) {
            sacc[tc] = __builtin_amdgcn_mfma_f32_16x16x32_bf16(aq0, bk0[tc], zero, 0, 0, 0);
            sacc[tc] = __builtin_amdgcn_mfma_f32_16x16x32_bf16(aq1, bk1[tc], sacc[tc], 0, 0, 0);
        }
        unsigned short* PsW = &Ps[w][0];
        if (kt == qt) {                       // diagonal tile (once per block)
            int rbase = 16 * w + quad * 4;
            #pragma unroll
            for (int tc = 0; tc < 4; ++tc) {
                int keyc = tc * 16 + lcol;
                #pragma unroll
                for (int r = 0; r < 4; ++r) {
                    float p = __builtin_amdgcn_exp2f(sacc[tc][r] * SC);
                    if (keyc > rbase + r) p = 0.f;
                    l[r] += p;
                    PsW[(quad * 4 + r) * PST + keyc] = f2bf(p);
                }
            }
        } else {                              // main path: no mask
            #pragma unroll
            for (int tc = 0; tc < 4; ++tc) {
                int keyc = tc * 16 + lcol;
                #pragma unroll
                for (int r = 0; r < 4; ++r) {
                    float p = __builtin_amdgcn_exp2f(sacc[tc][r] * SC);
                    l[r] += p;
                    PsW[(quad * 4 + r) * PST + keyc] = f2bf(p);
                }
            }
        }
        short8 ap0 = *(const short8*)(&PsW[lcol * PST + quad * 8]);
        short8 ap1 = *(const short8*)(&PsW[lcol * PST + 32 + quad * 8]);
        #pragma unroll
        for (int td = 0; td < 4; ++td) {
            O[td] = __builtin_amdgcn_mfma_f32_16x16x32_bf16(ap0, bv0[td], O[td], 0, 0, 0);
            O[td] = __builtin_amdgcn_mfma_f32_16x16x32_bf16(ap1, bv1[td], O[td], 0, 0, 0);
        }
    }

    #pragma unroll
    for (int r = 0; r < 4; ++r) {
        #pragma unroll
        for (int off = 1; off < 16; off <<= 1)
            l[r] += __shfl_xor(l[r], off, 64);
    }

    if (qt < 16) {
        int b = bh >> 4, h = bh & 15;
        size_t obase = ((size_t)b * SEQ) * EMB + (size_t)h * HD;
        #pragma unroll
        for (int td = 0; td < 4; ++td) {
            #pragma unroll
            for (int r = 0; r < 4; ++r) {
                int row = q0 + 16 * w + quad * 4 + r;
                Out[obase + (size_t)row * EMB + td * 16 + lcol] = f2bf(O[td][r] / l[r]);
            }
        }
    } else {
        float* slot = Part + ((size_t)(bh * 16 + (qt - 16)) * 2 + c) * SLOT_F;
        #pragma unroll
        for (int td = 0; td < 4; ++td) {
            #pragma unroll
            for (int r = 0; r < 4; ++r)
                slot[(16 * w + quad * 4 + r) * 64 + td * 16 + lcol] = O[td][r];
        }
        if (lcol == 0) {
            #pragma unroll
            for (int r = 0; r < 4; ++r)
                slot[4096 + 16 * w + quad * 4 + r] = l[r];
        }
    }
}

// merge the 2 partials per (bh, qt>=16) and write bf16 attn rows
__global__ __launch_bounds__(256) void attn_combine(
    const float* __restrict__ Part, unsigned short* __restrict__ Out)
{
    int qh = blockIdx.x;             // 0..15
    int bh = blockIdx.y;
    int qt = 16 + qh;
    const float* s0 = Part + ((size_t)(bh * 16 + qh) * 2) * SLOT_F;
    const float* s1 = s0 + SLOT_F;
    int b = bh >> 4, h = bh & 15;
    size_t obase = ((size_t)b * SEQ + qt * 64) * EMB + (size_t)h * HD;
    int t = threadIdx.x;
    #pragma unroll
    for (int it = 0; it < 16; ++it) {
        int idx = it * 256 + t;
        int row = idx >> 6, col = idx & 63;
        float lv = s0[4096 + row] + s1[4096 + row];
        float v = (s0[idx] + s1[idx]) / lv;
        Out[obase + (size_t)row * EMB + col] = f2bf(v);
    }
}

// ---------------------------------------------------------------------------
// Output projection, m97-style staging. fp32 bias, fp32 out.
// ---------------------------------------------------------------------------
__global__ __launch_bounds__(256) void oproj_gemm(
    const unsigned short* __restrict__ A,    // [4096][1024] bf16
    const unsigned short* __restrict__ Bt,   // W_o^T [1024][1024] bf16
    const float* __restrict__ bias,          // [1024] fp32
    float* __restrict__ Cout)                // [4096][1024] fp32
{
    const int K = EMB;
    __shared__ __align__(16) unsigned short As[128 * 32];
    __shared__ __align__(16) unsigned short Bs[128 * 32];
    int t = threadIdx.x;
    int m0 = blockIdx.y * 128;
    int n0 = blockIdx.x * 128;
    int w = t >> 6, lane = t & 63, quad = lane >> 4, lcol = lane & 15;
    int wr = w >> 1, wc = w & 1;

    floatx4 zero = {0.f, 0.f, 0.f, 0.f};
    floatx4 acc[4][4];
    #pragma unroll
    for (int i = 0; i < 4; ++i)
        #pragma unroll
        for (int j = 0; j < 4; ++j) acc[i][j] = zero;

    const unsigned short* a0 = A  + (size_t)(m0 + (t >> 2)) * K + ((t & 3) << 3);
    const unsigned short* b0 = Bt + (size_t)(n0 + (t >> 2)) * K + ((t & 3) << 3);
    unsigned short* la = &As[t << 3];
    unsigned short* lb = &Bs[t << 3];

    for (int k0 = 0; k0 < K; k0 += 32) {
        __syncthreads();
        GLL(a0 + k0, la);
        GLL(a0 + 64 * K + k0, la + 2048);
        GLL(b0 + k0, lb);
        GLL(b0 + 64 * K + k0, lb + 2048);
        __syncthreads();
        short8 af[4], bfm[4];
        #pragma unroll
        for (int i = 0; i < 4; ++i)
            af[i] = *(const short8*)(&As[(wr * 64 + i * 16 + lcol) * 32 + quad * 8]);
        #pragma unroll
        for (int j = 0; j < 4; ++j)
            bfm[j] = *(const short8*)(&Bs[(wc * 64 + j * 16 + lcol) * 32 + quad * 8]);
        #pragma unroll
        for (int i = 0; i < 4; ++i)
            #pragma unroll
            for (int j = 0; j < 4; ++j)
                acc[i][j] = __builtin_amdgcn_mfma_f32_16x16x32_bf16(af[i], bfm[j], acc[i][j], 0, 0, 0);
    }

    #pragma unroll
    for (int i = 0; i < 4; ++i) {
        int m = m0 + wr * 64 + i * 16 + quad * 4;
        #pragma unroll
        for (int j = 0; j < 4; ++j) {
            int n = n0 + wc * 64 + j * 16 + lcol;
            float bv = bias[n];
            #pragma unroll
            for (int r = 0; r < 4; ++r)
                Cout[(size_t)(m + r) * EMB + n] = acc[i][j][r] + bv;
        }
    }
}

// ---------------------------------------------------------------------------
extern "C" void kernel_launch(void* const* d_in, const int* in_sizes, int n_in,
                              void* d_out, int out_size, void* d_ws, size_t ws_size,
                              hipStream_t stream) {
    (void)in_sizes; (void)n_in; (void)out_size; (void)ws_size;
    char* ws = (char*)d_ws;
    const size_t OFF_X     = 0;                                      // 8 MB
    const size_t OFF_WQKVT = OFF_X     + (size_t)M_ROWS * EMB * 2;   // 6 MB
    const size_t OFF_WOT   = OFF_WQKVT + (size_t)N_QKV * EMB * 2;    // 2 MB
    const size_t OFF_Q     = OFF_WOT   + (size_t)EMB * EMB * 2;      // 8 MB
    const size_t OFF_K     = OFF_Q     + (size_t)M_ROWS * EMB * 2;   // 8 MB
    const size_t OFF_V     = OFF_K     + (size_t)M_ROWS * EMB * 2;   // 8 MB
    const size_t OFF_ATTN  = OFF_V     + (size_t)M_ROWS * EMB * 2;   // 8 MB
    const size_t OFF_PART  = OFF_ATTN  + (size_t)M_ROWS * EMB * 2;   // 17 MB

    const float* x    = (const float*)d_in[0];
    const float* Wqkv = (const float*)d_in[1];
    const float* bqkv = (const float*)d_in[2];
    const float* Wo   = (const float*)d_in[3];
    const float* bo   = (const float*)d_in[4];

    unsigned short* x_bf  = (unsigned short*)(ws + OFF_X);
    unsigned short* wqkvT = (unsigned short*)(ws + OFF_WQKVT);
    unsigned short* woT   = (unsigned short*)(ws + OFF_WOT);
    unsigned short* qb    = (unsigned short*)(ws + OFF_Q);
    unsigned short* kb    = (unsigned short*)(ws + OFF_K);
    unsigned short* vb    = (unsigned short*)(ws + OFF_V);    // [B,H,D,S]
    unsigned short* attn  = (unsigned short*)(ws + OFF_ATTN);
    float*          part  = (float*)(ws + OFF_PART);

    x_to_bf16<<<(M_ROWS * EMB / 4 + 255) / 256, 256, 0, stream>>>(x, x_bf, M_ROWS * EMB / 4);
    transpose_f32_bf16<<<dim3(N_QKV / 32, EMB / 32), dim3(32, 8), 0, stream>>>(Wqkv, wqkvT, EMB, N_QKV);
    transpose_f32_bf16<<<dim3(EMB / 32, EMB / 32), dim3(32, 8), 0, stream>>>(Wo, woT, EMB, EMB);

    qkv_gemm<<<dim3(N_QKV / 128, M_ROWS / 128), 256, 0, stream>>>(x_bf, wqkvT, bqkv, qb, kb, vb);
    attn_partial<<<dim3(48, NB * NH), 256, 0, stream>>>(qb, kb, vb, attn, part);
    attn_combine<<<dim3(16, NB * NH), 256, 0, stream>>>(part, attn);
    oproj_gemm<<<dim3(EMB / 128, M_ROWS / 128), 256, 0, stream>>>(attn, woT, bo, (float*)d_out);
}

// Round 9
// 217.869 us; speedup vs baseline: 1.3454x; 1.0308x over previous
//
#include <hip/hip_runtime.h>

// ---------------------------------------------------------------------------
// MultiHeadAttention: B=2, S=2048, E=1024, H=16, D=64, causal. fp32 I/O.
// R9: GEMM K-loops -> single-barrier double-buffered GLL pipeline (the R7
// attn pattern): barrier drains prev iter's loads, prefetch issues after the
// barrier and stays in flight across compute. R8's 2-barrier shape had zero
// intra-wave overlap (vmcnt(0) drain right after issue). Also fused the two
// weight transposes into one launch. attn/combine unchanged from R8.
// ---------------------------------------------------------------------------

typedef __attribute__((ext_vector_type(8))) short short8;
typedef __attribute__((ext_vector_type(4))) float floatx4;

#define NB 2
#define SEQ 2048
#define EMB 1024
#define NH 16
#define HD 64
#define M_ROWS (NB * SEQ)        // 4096
#define N_QKV (3 * EMB)          // 3072
#define SLOT_F 4160              // 64x64 O + 64 l (floats) per partial slot

#define GLL(g, l) __builtin_amdgcn_global_load_lds( \
    (const __attribute__((address_space(1))) void*)(g), \
    (__attribute__((address_space(3))) void*)(l), 16, 0, 0)

static __device__ __forceinline__ unsigned short f2bf(float f) {
    union { float f; unsigned int u; } v; v.f = f;
    unsigned int r = v.u + 0x7FFFu + ((v.u >> 16) & 1u);
    return (unsigned short)(r >> 16);
}

// x fp32 -> bf16 (4 elems / thread)
__global__ void x_to_bf16(const float* __restrict__ in, unsigned short* __restrict__ out, int n4) {
    int i = blockIdx.x * blockDim.x + threadIdx.x;
    if (i >= n4) return;
    float4 v = ((const float4*)in)[i];
    unsigned long long p = (unsigned long long)f2bf(v.x)
        | ((unsigned long long)f2bf(v.y) << 16)
        | ((unsigned long long)f2bf(v.z) << 32)
        | ((unsigned long long)f2bf(v.w) << 48);
    ((unsigned long long*)out)[i] = p;
}

// Fused: z=0 transposes W_qkv (1024 x 3072), z=1 transposes W_o (1024 x 1024).
__global__ void transpose_weights(const float* __restrict__ Wqkv, const float* __restrict__ Wo,
                                  unsigned short* __restrict__ wqkvT, unsigned short* __restrict__ woT) {
    __shared__ unsigned short tile[32][33];
    int z = blockIdx.z;
    int C = z ? EMB : N_QKV;
    if ((int)blockIdx.x * 32 >= C) return;
    const float* in = z ? Wo : Wqkv;
    unsigned short* out = z ? woT : wqkvT;
    const int R = EMB;
    int tx = threadIdx.x, ty = threadIdx.y;
    int c0 = blockIdx.x * 32, r0 = blockIdx.y * 32;
    #pragma unroll
    for (int j = 0; j < 4; ++j)
        tile[ty + j * 8][tx] = f2bf(in[(size_t)(r0 + ty + j * 8) * C + c0 + tx]);
    __syncthreads();
    #pragma unroll
    for (int j = 0; j < 4; ++j)
        out[(size_t)(c0 + ty + j * 8) * R + r0 + tx] = tile[tx][ty + j * 8];
}

// ---------------------------------------------------------------------------
// QKV GEMM: single-barrier dbuf GLL K-loop + LDS-roundtrip coalesced epilogue.
// Q,K -> [B,H,S,D]; V -> [B,H,D,S].
// ---------------------------------------------------------------------------
#define CTS 130   // C-tile LDS stride (shorts), pad 2

__global__ __launch_bounds__(256) void qkv_gemm(
    const unsigned short* __restrict__ A,    // x_bf [4096][1024]
    const unsigned short* __restrict__ Bt,   // W_qkv^T [3072][1024] bf16
    const float* __restrict__ bias,          // [3072] fp32
    unsigned short* __restrict__ qb, unsigned short* __restrict__ kb,
    unsigned short* __restrict__ vb)         // vb: [B,H,D,S]
{
    const int K = EMB;
    // union: dbuf staging (2 x (As 4096 + Bs 4096) shorts = 32 KB) | C-tile 128*130
    __shared__ __align__(16) unsigned short smem[128 * CTS];

    int t = threadIdx.x;
    int m0 = blockIdx.y * 128;
    int n0 = blockIdx.x * 128;
    int w = t >> 6, lane = t & 63, quad = lane >> 4, lcol = lane & 15;
    int wr = w >> 1, wc = w & 1;

    floatx4 zero = {0.f, 0.f, 0.f, 0.f};
    floatx4 acc[4][4];
    #pragma unroll
    for (int i = 0; i < 4; ++i)
        #pragma unroll
        for (int j = 0; j < 4; ++j) acc[i][j] = zero;

    const unsigned short* a0 = A  + (size_t)(m0 + (t >> 2)) * K + ((t & 3) << 3);
    const unsigned short* b0 = Bt + (size_t)(n0 + (t >> 2)) * K + ((t & 3) << 3);
    unsigned short* la = &smem[t << 3];          // + buf*8192 ; Bs at +4096

    // prologue: stage k0=0 into buf 0
    GLL(a0, la);
    GLL(a0 + 64 * K, la + 2048);
    GLL(b0, la + 4096);
    GLL(b0 + 64 * K, la + 6144);

    for (int k0 = 0; k0 < K; k0 += 32) {
        int cur = (k0 >> 5) & 1, nxt = cur ^ 1;
        __syncthreads();                         // drains cur's staging loads
        if (k0 + 32 < K) {                       // prefetch nxt AFTER barrier
            GLL(a0 + k0 + 32, la + nxt * 8192);
            GLL(a0 + 64 * K + k0 + 32, la + nxt * 8192 + 2048);
            GLL(b0 + k0 + 32, la + nxt * 8192 + 4096);
            GLL(b0 + 64 * K + k0 + 32, la + nxt * 8192 + 6144);
        }
        const unsigned short* As = &smem[cur * 8192];
        const unsigned short* Bs = As + 4096;
        short8 af[4], bfm[4];
        #pragma unroll
        for (int i = 0; i < 4; ++i)
            af[i] = *(const short8*)(&As[(wr * 64 + i * 16 + lcol) * 32 + quad * 8]);
        #pragma unroll
        for (int j = 0; j < 4; ++j)
            bfm[j] = *(const short8*)(&Bs[(wc * 64 + j * 16 + lcol) * 32 + quad * 8]);
        #pragma unroll
        for (int i = 0; i < 4; ++i)
            #pragma unroll
            for (int j = 0; j < 4; ++j)
                acc[i][j] = __builtin_amdgcn_mfma_f32_16x16x32_bf16(af[i], bfm[j], acc[i][j], 0, 0, 0);
    }

    // ---- epilogue: bias + bf16 into LDS C-tile, then coalesced streams ----
    bool isV = (n0 >= 2 * EMB);
    __syncthreads();                             // all staging reads done
    #pragma unroll
    for (int i = 0; i < 4; ++i) {
        int row0 = wr * 64 + i * 16 + quad * 4;
        #pragma unroll
        for (int j = 0; j < 4; ++j) {
            int col = wc * 64 + j * 16 + lcol;
            float bv = bias[n0 + col];
            #pragma unroll
            for (int r = 0; r < 4; ++r) {
                unsigned short hv = f2bf(acc[i][j][r] + bv);
                if (isV) smem[col * CTS + row0 + r] = hv;   // [feature][token]
                else     smem[(row0 + r) * CTS + col] = hv; // [token][feature]
            }
        }
    }
    __syncthreads();

    int b = m0 >> 11, s0 = m0 & 2047;
    int hbase = (n0 & 1023) >> 6;
    if (!isV) {
        unsigned short* dst = (n0 >= EMB) ? kb : qb;
        #pragma unroll
        for (int it = 0; it < 8; ++it) {
            int job = it * 32 + (t >> 3);    // 0..255
            int tok = job & 127, hh = job >> 7;
            int chunk = t & 7;
            short8 vv = *(const short8*)(&smem[tok * CTS + hh * 64 + chunk * 8]);
            size_t g = ((size_t)((b * NH + hbase + hh) * SEQ + s0 + tok)) * HD + chunk * 8;
            *(short8*)(&dst[g]) = vv;
        }
    } else {
        #pragma unroll
        for (int it = 0; it < 8; ++it) {
            int job = it * 32 + (t >> 3);    // 0..255
            int f = job & 127, half = job >> 7;
            int chunk = (t & 7) + half * 8;  // 0..15 token-chunks of 8
            short8 vv = *(const short8*)(&smem[f * CTS + chunk * 8]);
            int h = hbase + (f >> 6), d = f & 63;
            size_t g = ((size_t)((b * NH + h) * HD + d)) * SEQ + s0 + chunk * 8;
            *(short8*)(&vb[g]) = vv;
        }
    }
}

// ---------------------------------------------------------------------------
// Split-K flash attention, causal, fixed softmax base. Block (u, bh):
//   u<16:  qt=u, keys [0, qt+1)           -> final bf16 write
//   u>=16: qt=16+(u-16)/2, c=(u-16)&1, keys c0=[0,16) c1=[16,qt+1)
// GLL staging, XOR-swizzled segs; diagonal mask peeled to a uniform branch.
// ---------------------------------------------------------------------------
#define PST 68

__global__ __launch_bounds__(256) void attn_partial(
    const unsigned short* __restrict__ Q,   // [B*H][S][D]
    const unsigned short* __restrict__ Kk,  // [B*H][S][D]
    const unsigned short* __restrict__ Vt,  // [B*H][D][S]
    unsigned short* __restrict__ Out,       // [b][s][h*64+d]
    float* __restrict__ Part)               // partial slots
{
    __shared__ __align__(16) unsigned short Ks[2][64 * 64];
    __shared__ __align__(16) unsigned short Vs[2][64 * 64];
    __shared__ __align__(16) unsigned short Ps[4][16 * PST];

    int u = blockIdx.x;              // 0..47
    int bh = blockIdx.y;
    int qt, c;
    if (u < 16) { qt = u; c = 0; }
    else { int v = u - 16; qt = 16 + (v >> 1); c = v & 1; }
    int ktBeg = c << 4;
    int ktEnd = (c == 0 && qt >= 16) ? 16 : (qt + 1);

    int q0 = qt * 64;
    int t = threadIdx.x;
    int w = t >> 6, lane = t & 63, quad = lane >> 4, lcol = lane & 15;
    const size_t hoff = (size_t)bh * SEQ * HD;
    const float SC = 0.18033688011112043f;   // (1/sqrt(64)) * log2(e)

    const unsigned short* qp = Q + hoff + (size_t)(q0 + 16 * w + lcol) * HD + quad * 8;
    short8 aq0 = *(const short8*)qp, aq1 = *(const short8*)(qp + 32);

    int srow = t >> 3;                       // 0..31
    int ss   = (t & 7) ^ (srow & 7);
    const unsigned short* kgl = Kk + hoff + (size_t)srow * HD + ss * 8;
    const unsigned short* vgl = Vt + hoff + (size_t)srow * SEQ + ss * 8;
    unsigned short* kld = &Ks[0][t * 8];
    unsigned short* vld = &Vs[0][t * 8];

    floatx4 zero = {0.f, 0.f, 0.f, 0.f};
    floatx4 O[4];
    float l[4] = {0.f, 0.f, 0.f, 0.f};
    #pragma unroll
    for (int d = 0; d < 4; ++d) O[d] = zero;

    {   // prologue: stage tile ktBeg into buf 0 (ktBeg is even)
        int k0 = ktBeg * 64;
        GLL(kgl + (size_t)k0 * HD, kld);
        GLL(kgl + (size_t)(k0 + 32) * HD, kld + 2048);
        GLL(vgl + k0, vld);
        GLL(vgl + (size_t)32 * SEQ + k0, vld + 2048);
    }

    int sx0 = (quad ^ (lcol & 7)) << 3;
    int sx1 = sx0 ^ 32;

    for (int kt = ktBeg; kt < ktEnd; ++kt) {
        int cur = kt & 1, nxt = cur ^ 1;
        __syncthreads();                     // drains tile-kt staging loads
        if (kt + 1 < ktEnd) {
            int k0 = (kt + 1) * 64;
            GLL(kgl + (size_t)k0 * HD, kld + nxt * 4096);
            GLL(kgl + (size_t)(k0 + 32) * HD, kld + nxt * 4096 + 2048);
            GLL(vgl + k0, vld + nxt * 4096);
            GLL(vgl + (size_t)32 * SEQ + k0, vld + nxt * 4096 + 2048);
        }

        const unsigned short* ksr = &Ks[cur][0];
        const unsigned short* vsr = &Vs[cur][0];
        short8 bk0[4], bk1[4], bv0[4], bv1[4];
        #pragma unroll
        for (int tc = 0; tc < 4; ++tc) {
            int rb = (tc * 16 + lcol) << 6;
            bk0[tc] = *(const short8*)(ksr + rb + sx0);
            bk1[tc] = *(const short8*)(ksr + rb + sx1);
            bv0[tc] = *(const short8*)(vsr + rb + sx0);
            bv1[tc] = *(const short8*)(vsr + rb + sx1);
        }

        floatx4 sacc[4];
        #pragma unroll
        for (int tc = 0; tc < 4; ++tc) {
            sacc[tc] = __builtin_amdgcn_mfma_f32_16x16x32_bf16(aq0, bk0[tc], zero, 0, 0, 0);
            sacc[tc] = __builtin_amdgcn_mfma_f32_16x16x32_bf16(aq1, bk1[tc], sacc[tc], 0, 0, 0);
        }
        unsigned short* PsW = &Ps[w][0];
        if (kt == qt) {                       // diagonal tile (once per block)
            int rbase = 16 * w + quad * 4;
            #pragma unroll
            for (int tc = 0; tc < 4; ++tc) {
                int keyc = tc * 16 + lcol;
                #pragma unroll
                for (int r = 0; r < 4; ++r) {
                    float p = __builtin_amdgcn_exp2f(sacc[tc][r] * SC);
                    if (keyc > rbase + r) p = 0.f;
                    l[r] += p;
                    PsW[(quad * 4 + r) * PST + keyc] = f2bf(p);
                }
            }
        } else {                              // main path: no mask
            #pragma unroll
            for (int tc = 0; tc < 4; ++tc) {
                int keyc = tc * 16 + lcol;
                #pragma unroll
                for (int r = 0; r < 4; ++r) {
                    float p = __builtin_amdgcn_exp2f(sacc[tc][r] * SC);
                    l[r] += p;
                    PsW[(quad * 4 + r) * PST + keyc] = f2bf(p);
                }
            }
        }
        short8 ap0 = *(const short8*)(&PsW[lcol * PST + quad * 8]);
        short8 ap1 = *(const short8*)(&PsW[lcol * PST + 32 + quad * 8]);
        #pragma unroll
        for (int td = 0; td < 4; ++td) {
            O[td] = __builtin_amdgcn_mfma_f32_16x16x32_bf16(ap0, bv0[td], O[td], 0, 0, 0);
            O[td] = __builtin_amdgcn_mfma_f32_16x16x32_bf16(ap1, bv1[td], O[td], 0, 0, 0);
        }
    }

    #pragma unroll
    for (int r = 0; r < 4; ++r) {
        #pragma unroll
        for (int off = 1; off < 16; off <<= 1)
            l[r] += __shfl_xor(l[r], off, 64);
    }

    if (qt < 16) {
        int b = bh >> 4, h = bh & 15;
        size_t obase = ((size_t)b * SEQ) * EMB + (size_t)h * HD;
        #pragma unroll
        for (int td = 0; td < 4; ++td) {
            #pragma unroll
            for (int r = 0; r < 4; ++r) {
                int row = q0 + 16 * w + quad * 4 + r;
                Out[obase + (size_t)row * EMB + td * 16 + lcol] = f2bf(O[td][r] / l[r]);
            }
        }
    } else {
        float* slot = Part + ((size_t)(bh * 16 + (qt - 16)) * 2 + c) * SLOT_F;
        #pragma unroll
        for (int td = 0; td < 4; ++td) {
            #pragma unroll
            for (int r = 0; r < 4; ++r)
                slot[(16 * w + quad * 4 + r) * 64 + td * 16 + lcol] = O[td][r];
        }
        if (lcol == 0) {
            #pragma unroll
            for (int r = 0; r < 4; ++r)
                slot[4096 + 16 * w + quad * 4 + r] = l[r];
        }
    }
}

// merge the 2 partials per (bh, qt>=16) and write bf16 attn rows
__global__ __launch_bounds__(256) void attn_combine(
    const float* __restrict__ Part, unsigned short* __restrict__ Out)
{
    int qh = blockIdx.x;             // 0..15
    int bh = blockIdx.y;
    int qt = 16 + qh;
    const float* s0 = Part + ((size_t)(bh * 16 + qh) * 2) * SLOT_F;
    const float* s1 = s0 + SLOT_F;
    int b = bh >> 4, h = bh & 15;
    size_t obase = ((size_t)b * SEQ + qt * 64) * EMB + (size_t)h * HD;
    int t = threadIdx.x;
    #pragma unroll
    for (int it = 0; it < 16; ++it) {
        int idx = it * 256 + t;
        int row = idx >> 6, col = idx & 63;
        float lv = s0[4096 + row] + s1[4096 + row];
        float v = (s0[idx] + s1[idx]) / lv;
        Out[obase + (size_t)row * EMB + col] = f2bf(v);
    }
}

// ---------------------------------------------------------------------------
// Output projection: single-barrier dbuf GLL K-loop. fp32 bias, fp32 out.
// ---------------------------------------------------------------------------
__global__ __launch_bounds__(256) void oproj_gemm(
    const unsigned short* __restrict__ A,    // [4096][1024] bf16
    const unsigned short* __restrict__ Bt,   // W_o^T [1024][1024] bf16
    const float* __restrict__ bias,          // [1024] fp32
    float* __restrict__ Cout)                // [4096][1024] fp32
{
    const int K = EMB;
    __shared__ __align__(16) unsigned short smem[2 * 8192];
    int t = threadIdx.x;
    int m0 = blockIdx.y * 128;
    int n0 = blockIdx.x * 128;
    int w = t >> 6, lane = t & 63, quad = lane >> 4, lcol = lane & 15;
    int wr = w >> 1, wc = w & 1;

    floatx4 zero = {0.f, 0.f, 0.f, 0.f};
    floatx4 acc[4][4];
    #pragma unroll
    for (int i = 0; i < 4; ++i)
        #pragma unroll
        for (int j = 0; j < 4; ++j) acc[i][j] = zero;

    const unsigned short* a0 = A  + (size_t)(m0 + (t >> 2)) * K + ((t & 3) << 3);
    const unsigned short* b0 = Bt + (size_t)(n0 + (t >> 2)) * K + ((t & 3) << 3);
    unsigned short* la = &smem[t << 3];

    GLL(a0, la);
    GLL(a0 + 64 * K, la + 2048);
    GLL(b0, la + 4096);
    GLL(b0 + 64 * K, la + 6144);

    for (int k0 = 0; k0 < K; k0 += 32) {
        int cur = (k0 >> 5) & 1, nxt = cur ^ 1;
        __syncthreads();
        if (k0 + 32 < K) {
            GLL(a0 + k0 + 32, la + nxt * 8192);
            GLL(a0 + 64 * K + k0 + 32, la + nxt * 8192 + 2048);
            GLL(b0 + k0 + 32, la + nxt * 8192 + 4096);
            GLL(b0 + 64 * K + k0 + 32, la + nxt * 8192 + 6144);
        }
        const unsigned short* As = &smem[cur * 8192];
        const unsigned short* Bs = As + 4096;
        short8 af[4], bfm[4];
        #pragma unroll
        for (int i = 0; i < 4; ++i)
            af[i] = *(const short8*)(&As[(wr * 64 + i * 16 + lcol) * 32 + quad * 8]);
        #pragma unroll
        for (int j = 0; j < 4; ++j)
            bfm[j] = *(const short8*)(&Bs[(wc * 64 + j * 16 + lcol) * 32 + quad * 8]);
        #pragma unroll
        for (int i = 0; i < 4; ++i)
            #pragma unroll
            for (int j = 0; j < 4; ++j)
                acc[i][j] = __builtin_amdgcn_mfma_f32_16x16x32_bf16(af[i], bfm[j], acc[i][j], 0, 0, 0);
    }

    #pragma unroll
    for (int i = 0; i < 4; ++i) {
        int m = m0 + wr * 64 + i * 16 + quad * 4;
        #pragma unroll
        for (int j = 0; j < 4; ++j) {
            int n = n0 + wc * 64 + j * 16 + lcol;
            float bv = bias[n];
            #pragma unroll
            for (int r = 0; r < 4; ++r)
                Cout[(size_t)(m + r) * EMB + n] = acc[i][j][r] + bv;
        }
    }
}

// ---------------------------------------------------------------------------
extern "C" void kernel_launch(void* const* d_in, const int* in_sizes, int n_in,
                              void* d_out, int out_size, void* d_ws, size_t ws_size,
                              hipStream_t stream) {
    (void)in_sizes; (void)n_in; (void)out_size; (void)ws_size;
    char* ws = (char*)d_ws;
    const size_t OFF_X     = 0;                                      // 8 MB
    const size_t OFF_WQKVT = OFF_X     + (size_t)M_ROWS * EMB * 2;   // 6 MB
    const size_t OFF_WOT   = OFF_WQKVT + (size_t)N_QKV * EMB * 2;    // 2 MB
    const size_t OFF_Q     = OFF_WOT   + (size_t)EMB * EMB * 2;      // 8 MB
    const size_t OFF_K     = OFF_Q     + (size_t)M_ROWS * EMB * 2;   // 8 MB
    const size_t OFF_V     = OFF_K     + (size_t)M_ROWS * EMB * 2;   // 8 MB
    const size_t OFF_ATTN  = OFF_V     + (size_t)M_ROWS * EMB * 2;   // 8 MB
    const size_t OFF_PART  = OFF_ATTN  + (size_t)M_ROWS * EMB * 2;   // 17 MB

    const float* x    = (const float*)d_in[0];
    const float* Wqkv = (const float*)d_in[1];
    const float* bqkv = (const float*)d_in[2];
    const float* Wo   = (const float*)d_in[3];
    const float* bo   = (const float*)d_in[4];

    unsigned short* x_bf  = (unsigned short*)(ws + OFF_X);
    unsigned short* wqkvT = (unsigned short*)(ws + OFF_WQKVT);
    unsigned short* woT   = (unsigned short*)(ws + OFF_WOT);
    unsigned short* qb    = (unsigned short*)(ws + OFF_Q);
    unsigned short* kb    = (unsigned short*)(ws + OFF_K);
    unsigned short* vb    = (unsigned short*)(ws + OFF_V);    // [B,H,D,S]
    unsigned short* attn  = (unsigned short*)(ws + OFF_ATTN);
    float*          part  = (float*)(ws + OFF_PART);

    x_to_bf16<<<(M_ROWS * EMB / 4 + 255) / 256, 256, 0, stream>>>(x, x_bf, M_ROWS * EMB / 4);
    transpose_weights<<<dim3(N_QKV / 32, EMB / 32, 2), dim3(32, 8), 0, stream>>>(Wqkv, Wo, wqkvT, woT);

    qkv_gemm<<<dim3(N_QKV / 128, M_ROWS / 128), 256, 0, stream>>>(x_bf, wqkvT, bqkv, qb, kb, vb);
    attn_partial<<<dim3(48, NB * NH), 256, 0, stream>>>(qb, kb, vb, attn, part);
    attn_combine<<<dim3(16, NB * NH), 256, 0, stream>>>(part, attn);
    oproj_gemm<<<dim3(EMB / 128, M_ROWS / 128), 256, 0, stream>>>(attn, woT, bo, (float*)d_out);
}

// Round 10
// 212.525 us; speedup vs baseline: 1.3792x; 1.0251x over previous
//
#include <hip/hip_runtime.h>

// ---------------------------------------------------------------------------
// MultiHeadAttention: B=2, S=2048, E=1024, H=16, D=64, causal. fp32 I/O.
// R10: attn: (a) l computed by MFMA ones-trick (P @ 1s = row sums; every lane
// gets its rows' l -> no per-iter adds, no final shuffle reduce); (b) partial
// O slots stored bf16 (l fp32). Prep kernels fused into one launch.
// GEMMs unchanged from R9 (single-barrier dbuf GLL).
// ---------------------------------------------------------------------------

typedef __attribute__((ext_vector_type(8))) short short8;
typedef __attribute__((ext_vector_type(4))) float floatx4;

#define NB 2
#define SEQ 2048
#define EMB 1024
#define NH 16
#define HD 64
#define M_ROWS (NB * SEQ)        // 4096
#define N_QKV (3 * EMB)          // 3072
#define SLOT_B 8448              // bytes: 64x64 bf16 O (8192) + 64 fp32 l (256)

#define GLL(g, l) __builtin_amdgcn_global_load_lds( \
    (const __attribute__((address_space(1))) void*)(g), \
    (__attribute__((address_space(3))) void*)(l), 16, 0, 0)

static __device__ __forceinline__ unsigned short f2bf(float f) {
    union { float f; unsigned int u; } v; v.f = f;
    unsigned int r = v.u + 0x7FFFu + ((v.u >> 16) & 1u);
    return (unsigned short)(r >> 16);
}
static __device__ __forceinline__ float bf2f(unsigned short h) {
    union { unsigned int u; float f; } v; v.u = ((unsigned int)h) << 16;
    return v.f;
}

// Fused prep: z=0 transpose W_qkv, z=1 transpose W_o, z=2 convert x -> bf16.
__global__ void prep(const float* __restrict__ x,
                     const float* __restrict__ Wqkv, const float* __restrict__ Wo,
                     unsigned short* __restrict__ x_bf,
                     unsigned short* __restrict__ wqkvT, unsigned short* __restrict__ woT) {
    __shared__ unsigned short tile[32][33];
    int z = blockIdx.z;
    int tx = threadIdx.x, ty = threadIdx.y;
    if (z == 2) {
        int id = ((int)blockIdx.y * 96 + (int)blockIdx.x) * 256 + ty * 32 + tx;
        const int n4 = M_ROWS * EMB / 4;
        for (int i = id; i < n4; i += 96 * 32 * 256) {
            float4 v = ((const float4*)x)[i];
            unsigned long long p = (unsigned long long)f2bf(v.x)
                | ((unsigned long long)f2bf(v.y) << 16)
                | ((unsigned long long)f2bf(v.z) << 32)
                | ((unsigned long long)f2bf(v.w) << 48);
            ((unsigned long long*)x_bf)[i] = p;
        }
        return;
    }
    int C = z ? EMB : N_QKV;
    if ((int)blockIdx.x * 32 >= C) return;
    const float* in = z ? Wo : Wqkv;
    unsigned short* out = z ? woT : wqkvT;
    const int R = EMB;
    int c0 = blockIdx.x * 32, r0 = blockIdx.y * 32;
    #pragma unroll
    for (int j = 0; j < 4; ++j)
        tile[ty + j * 8][tx] = f2bf(in[(size_t)(r0 + ty + j * 8) * C + c0 + tx]);
    __syncthreads();
    #pragma unroll
    for (int j = 0; j < 4; ++j)
        out[(size_t)(c0 + ty + j * 8) * R + r0 + tx] = tile[tx][ty + j * 8];
}

// ---------------------------------------------------------------------------
// QKV GEMM: single-barrier dbuf GLL K-loop + LDS-roundtrip coalesced epilogue.
// Q,K -> [B,H,S,D]; V -> [B,H,D,S].
// ---------------------------------------------------------------------------
#define CTS 130   // C-tile LDS stride (shorts), pad 2

__global__ __launch_bounds__(256) void qkv_gemm(
    const unsigned short* __restrict__ A,    // x_bf [4096][1024]
    const unsigned short* __restrict__ Bt,   // W_qkv^T [3072][1024] bf16
    const float* __restrict__ bias,          // [3072] fp32
    unsigned short* __restrict__ qb, unsigned short* __restrict__ kb,
    unsigned short* __restrict__ vb)         // vb: [B,H,D,S]
{
    const int K = EMB;
    __shared__ __align__(16) unsigned short smem[128 * CTS];

    int t = threadIdx.x;
    int m0 = blockIdx.y * 128;
    int n0 = blockIdx.x * 128;
    int w = t >> 6, lane = t & 63, quad = lane >> 4, lcol = lane & 15;
    int wr = w >> 1, wc = w & 1;

    floatx4 zero = {0.f, 0.f, 0.f, 0.f};
    floatx4 acc[4][4];
    #pragma unroll
    for (int i = 0; i < 4; ++i)
        #pragma unroll
        for (int j = 0; j < 4; ++j) acc[i][j] = zero;

    const unsigned short* a0 = A  + (size_t)(m0 + (t >> 2)) * K + ((t & 3) << 3);
    const unsigned short* b0 = Bt + (size_t)(n0 + (t >> 2)) * K + ((t & 3) << 3);
    unsigned short* la = &smem[t << 3];          // + buf*8192 ; Bs at +4096

    GLL(a0, la);
    GLL(a0 + 64 * K, la + 2048);
    GLL(b0, la + 4096);
    GLL(b0 + 64 * K, la + 6144);

    for (int k0 = 0; k0 < K; k0 += 32) {
        int cur = (k0 >> 5) & 1, nxt = cur ^ 1;
        __syncthreads();                         // drains cur's staging loads
        if (k0 + 32 < K) {                       // prefetch nxt AFTER barrier
            GLL(a0 + k0 + 32, la + nxt * 8192);
            GLL(a0 + 64 * K + k0 + 32, la + nxt * 8192 + 2048);
            GLL(b0 + k0 + 32, la + nxt * 8192 + 4096);
            GLL(b0 + 64 * K + k0 + 32, la + nxt * 8192 + 6144);
        }
        const unsigned short* As = &smem[cur * 8192];
        const unsigned short* Bs = As + 4096;
        short8 af[4], bfm[4];
        #pragma unroll
        for (int i = 0; i < 4; ++i)
            af[i] = *(const short8*)(&As[(wr * 64 + i * 16 + lcol) * 32 + quad * 8]);
        #pragma unroll
        for (int j = 0; j < 4; ++j)
            bfm[j] = *(const short8*)(&Bs[(wc * 64 + j * 16 + lcol) * 32 + quad * 8]);
        #pragma unroll
        for (int i = 0; i < 4; ++i)
            #pragma unroll
            for (int j = 0; j < 4; ++j)
                acc[i][j] = __builtin_amdgcn_mfma_f32_16x16x32_bf16(af[i], bfm[j], acc[i][j], 0, 0, 0);
    }

    // ---- epilogue: bias + bf16 into LDS C-tile, then coalesced streams ----
    bool isV = (n0 >= 2 * EMB);
    __syncthreads();
    #pragma unroll
    for (int i = 0; i < 4; ++i) {
        int row0 = wr * 64 + i * 16 + quad * 4;
        #pragma unroll
        for (int j = 0; j < 4; ++j) {
            int col = wc * 64 + j * 16 + lcol;
            float bv = bias[n0 + col];
            #pragma unroll
            for (int r = 0; r < 4; ++r) {
                unsigned short hv = f2bf(acc[i][j][r] + bv);
                if (isV) smem[col * CTS + row0 + r] = hv;   // [feature][token]
                else     smem[(row0 + r) * CTS + col] = hv; // [token][feature]
            }
        }
    }
    __syncthreads();

    int b = m0 >> 11, s0 = m0 & 2047;
    int hbase = (n0 & 1023) >> 6;
    if (!isV) {
        unsigned short* dst = (n0 >= EMB) ? kb : qb;
        #pragma unroll
        for (int it = 0; it < 8; ++it) {
            int job = it * 32 + (t >> 3);
            int tok = job & 127, hh = job >> 7;
            int chunk = t & 7;
            short8 vv = *(const short8*)(&smem[tok * CTS + hh * 64 + chunk * 8]);
            size_t g = ((size_t)((b * NH + hbase + hh) * SEQ + s0 + tok)) * HD + chunk * 8;
            *(short8*)(&dst[g]) = vv;
        }
    } else {
        #pragma unroll
        for (int it = 0; it < 8; ++it) {
            int job = it * 32 + (t >> 3);
            int f = job & 127, half = job >> 7;
            int chunk = (t & 7) + half * 8;
            short8 vv = *(const short8*)(&smem[f * CTS + chunk * 8]);
            int h = hbase + (f >> 6), d = f & 63;
            size_t g = ((size_t)((b * NH + h) * HD + d)) * SEQ + s0 + chunk * 8;
            *(short8*)(&vb[g]) = vv;
        }
    }
}

// ---------------------------------------------------------------------------
// Split-K flash attention, causal, fixed softmax base. Block (u, bh):
//   u<16:  qt=u, keys [0, qt+1)           -> final bf16 write
//   u>=16: qt=16+(u-16)/2, c=(u-16)&1, keys c0=[0,16) c1=[16,qt+1)
// GLL staging, XOR-swizzled segs; diagonal mask peeled; l via MFMA ones-trick.
// ---------------------------------------------------------------------------
#define PST 68

__global__ __launch_bounds__(256) void attn_partial(
    const unsigned short* __restrict__ Q,   // [B*H][S][D]
    const unsigned short* __restrict__ Kk,  // [B*H][S][D]
    const unsigned short* __restrict__ Vt,  // [B*H][D][S]
    unsigned short* __restrict__ Out,       // [b][s][h*64+d]
    unsigned char* __restrict__ Part)       // partial slots (bf16 O + fp32 l)
{
    __shared__ __align__(16) unsigned short Ks[2][64 * 64];
    __shared__ __align__(16) unsigned short Vs[2][64 * 64];
    __shared__ __align__(16) unsigned short Ps[4][16 * PST];

    int u = blockIdx.x;              // 0..47
    int bh = blockIdx.y;
    int qt, c;
    if (u < 16) { qt = u; c = 0; }
    else { int v = u - 16; qt = 16 + (v >> 1); c = v & 1; }
    int ktBeg = c << 4;
    int ktEnd = (c == 0 && qt >= 16) ? 16 : (qt + 1);

    int q0 = qt * 64;
    int t = threadIdx.x;
    int w = t >> 6, lane = t & 63, quad = lane >> 4, lcol = lane & 15;
    const size_t hoff = (size_t)bh * SEQ * HD;
    const float SC = 0.18033688011112043f;   // (1/sqrt(64)) * log2(e)

    const unsigned short* qp = Q + hoff + (size_t)(q0 + 16 * w + lcol) * HD + quad * 8;
    short8 aq0 = *(const short8*)qp, aq1 = *(const short8*)(qp + 32);

    int srow = t >> 3;                       // 0..31
    int ss   = (t & 7) ^ (srow & 7);
    const unsigned short* kgl = Kk + hoff + (size_t)srow * HD + ss * 8;
    const unsigned short* vgl = Vt + hoff + (size_t)srow * SEQ + ss * 8;
    unsigned short* kld = &Ks[0][t * 8];
    unsigned short* vld = &Vs[0][t * 8];

    floatx4 zero = {0.f, 0.f, 0.f, 0.f};
    floatx4 O[4];
    floatx4 lacc = zero;                     // l via ones-MFMA (all lanes valid)
    #pragma unroll
    for (int d = 0; d < 4; ++d) O[d] = zero;

    short8 ones;                             // bf16 1.0 splat
    #pragma unroll
    for (int j = 0; j < 8; ++j) ones[j] = (short)0x3F80;

    {   // prologue: stage tile ktBeg into buf 0 (ktBeg is even)
        int k0 = ktBeg * 64;
        GLL(kgl + (size_t)k0 * HD, kld);
        GLL(kgl + (size_t)(k0 + 32) * HD, kld + 2048);
        GLL(vgl + k0, vld);
        GLL(vgl + (size_t)32 * SEQ + k0, vld + 2048);
    }

    int sx0 = (quad ^ (lcol & 7)) << 3;
    int sx1 = sx0 ^ 32;

    for (int kt = ktBeg; kt < ktEnd; ++kt) {
        int cur = kt & 1, nxt = cur ^ 1;
        __syncthreads();                     // drains tile-kt staging loads
        if (kt + 1 < ktEnd) {
            int k0 = (kt + 1) * 64;
            GLL(kgl + (size_t)k0 * HD, kld + nxt * 4096);
            GLL(kgl + (size_t)(k0 + 32) * HD, kld + nxt * 4096 + 2048);
            GLL(vgl + k0, vld + nxt * 4096);
            GLL(vgl + (size_t)32 * SEQ + k0, vld + nxt * 4096 + 2048);
        }

        const unsigned short* ksr = &Ks[cur][0];
        const unsigned short* vsr = &Vs[cur][0];
        short8 bk0[4], bk1[4], bv0[4], bv1[4];
        #pragma unroll
        for (int tc = 0; tc < 4; ++tc) {
            int rb = (tc * 16 + lcol) << 6;
            bk0[tc] = *(const short8*)(ksr + rb + sx0);
            bk1[tc] = *(const short8*)(ksr + rb + sx1);
            bv0[tc] = *(const short8*)(vsr + rb + sx0);
            bv1[tc] = *(const short8*)(vsr + rb + sx1);
        }

        floatx4 sacc[4];
        #pragma unroll
        for (int tc = 0; tc < 4; ++tc) {
            sacc[tc] = __builtin_amdgcn_mfma_f32_16x16x32_bf16(aq0, bk0[tc], zero, 0, 0, 0);
            sacc[tc] = __builtin_amdgcn_mfma_f32_16x16x32_bf16(aq1, bk1[tc], sacc[tc], 0, 0, 0);
        }
        unsigned short* PsW = &Ps[w][0];
        if (kt == qt) {                       // diagonal tile (once per block)
            int rbase = 16 * w + quad * 4;
            #pragma unroll
            for (int tc = 0; tc < 4; ++tc) {
                int keyc = tc * 16 + lcol;
                #pragma unroll
                for (int r = 0; r < 4; ++r) {
                    float p = __builtin_amdgcn_exp2f(sacc[tc][r] * SC);
                    if (keyc > rbase + r) p = 0.f;
                    PsW[(quad * 4 + r) * PST + keyc] = f2bf(p);
                }
            }
        } else {                              // main path: no mask
            #pragma unroll
            for (int tc = 0; tc < 4; ++tc) {
                int keyc = tc * 16 + lcol;
                #pragma unroll
                for (int r = 0; r < 4; ++r) {
                    float p = __builtin_amdgcn_exp2f(sacc[tc][r] * SC);
                    PsW[(quad * 4 + r) * PST + keyc] = f2bf(p);
                }
            }
        }
        short8 ap0 = *(const short8*)(&PsW[lcol * PST + quad * 8]);
        short8 ap1 = *(const short8*)(&PsW[lcol * PST + 32 + quad * 8]);
        #pragma unroll
        for (int td = 0; td < 4; ++td) {
            O[td] = __builtin_amdgcn_mfma_f32_16x16x32_bf16(ap0, bv0[td], O[td], 0, 0, 0);
            O[td] = __builtin_amdgcn_mfma_f32_16x16x32_bf16(ap1, bv1[td], O[td], 0, 0, 0);
        }
        // l += P @ 1s : every output column equals the row sum, so every lane
        // holds l for its rows (row = quad*4 + r) regardless of lcol.
        lacc = __builtin_amdgcn_mfma_f32_16x16x32_bf16(ap0, ones, lacc, 0, 0, 0);
        lacc = __builtin_amdgcn_mfma_f32_16x16x32_bf16(ap1, ones, lacc, 0, 0, 0);
    }

    if (qt < 16) {
        int b = bh >> 4, h = bh & 15;
        size_t obase = ((size_t)b * SEQ) * EMB + (size_t)h * HD;
        float inv[4];
        #pragma unroll
        for (int r = 0; r < 4; ++r) inv[r] = 1.0f / lacc[r];
        #pragma unroll
        for (int td = 0; td < 4; ++td) {
            #pragma unroll
            for (int r = 0; r < 4; ++r) {
                int row = q0 + 16 * w + quad * 4 + r;
                Out[obase + (size_t)row * EMB + td * 16 + lcol] = f2bf(O[td][r] * inv[r]);
            }
        }
    } else {
        unsigned char* sp = Part + ((size_t)(bh * 16 + (qt - 16)) * 2 + c) * SLOT_B;
        unsigned short* sO = (unsigned short*)sp;
        float* sL = (float*)(sp + 8192);
        #pragma unroll
        for (int td = 0; td < 4; ++td) {
            #pragma unroll
            for (int r = 0; r < 4; ++r)
                sO[(16 * w + quad * 4 + r) * 64 + td * 16 + lcol] = f2bf(O[td][r]);
        }
        if (lcol == 0) {
            #pragma unroll
            for (int r = 0; r < 4; ++r)
                sL[16 * w + quad * 4 + r] = lacc[r];
        }
    }
}

// merge the 2 partials per (bh, qt>=16) and write bf16 attn rows
__global__ __launch_bounds__(256) void attn_combine(
    const unsigned char* __restrict__ Part, unsigned short* __restrict__ Out)
{
    int qh = blockIdx.x;             // 0..15
    int bh = blockIdx.y;
    int qt = 16 + qh;
    const unsigned char* s0 = Part + ((size_t)(bh * 16 + qh) * 2) * SLOT_B;
    const unsigned char* s1 = s0 + SLOT_B;
    const unsigned short* O0 = (const unsigned short*)s0;
    const unsigned short* O1 = (const unsigned short*)s1;
    const float* L0 = (const float*)(s0 + 8192);
    const float* L1 = (const float*)(s1 + 8192);
    int b = bh >> 4, h = bh & 15;
    size_t obase = ((size_t)b * SEQ + qt * 64) * EMB + (size_t)h * HD;
    int t = threadIdx.x;
    #pragma unroll
    for (int it = 0; it < 16; ++it) {
        int idx = it * 256 + t;
        int row = idx >> 6, col = idx & 63;
        float lv = L0[row] + L1[row];
        float v = (bf2f(O0[idx]) + bf2f(O1[idx])) / lv;
        Out[obase + (size_t)row * EMB + col] = f2bf(v);
    }
}

// ---------------------------------------------------------------------------
// Output projection: single-barrier dbuf GLL K-loop. fp32 bias, fp32 out.
// ---------------------------------------------------------------------------
__global__ __launch_bounds__(256) void oproj_gemm(
    const unsigned short* __restrict__ A,    // [4096][1024] bf16
    const unsigned short* __restrict__ Bt,   // W_o^T [1024][1024] bf16
    const float* __restrict__ bias,          // [1024] fp32
    float* __restrict__ Cout)                // [4096][1024] fp32
{
    const int K = EMB;
    __shared__ __align__(16) unsigned short smem[2 * 8192];
    int t = threadIdx.x;
    int m0 = blockIdx.y * 128;
    int n0 = blockIdx.x * 128;
    int w = t >> 6, lane = t & 63, quad = lane >> 4, lcol = lane & 15;
    int wr = w >> 1, wc = w & 1;

    floatx4 zero = {0.f, 0.f, 0.f, 0.f};
    floatx4 acc[4][4];
    #pragma unroll
    for (int i = 0; i < 4; ++i)
        #pragma unroll
        for (int j = 0; j < 4; ++j) acc[i][j] = zero;

    const unsigned short* a0 = A  + (size_t)(m0 + (t >> 2)) * K + ((t & 3) << 3);
    const unsigned short* b0 = Bt + (size_t)(n0 + (t >> 2)) * K + ((t & 3) << 3);
    unsigned short* la = &smem[t << 3];

    GLL(a0, la);
    GLL(a0 + 64 * K, la + 2048);
    GLL(b0, la + 4096);
    GLL(b0 + 64 * K, la + 6144);

    for (int k0 = 0; k0 < K; k0 += 32) {
        int cur = (k0 >> 5) & 1, nxt = cur ^ 1;
        __syncthreads();
        if (k0 + 32 < K) {
            GLL(a0 + k0 + 32, la + nxt * 8192);
            GLL(a0 + 64 * K + k0 + 32, la + nxt * 8192 + 2048);
            GLL(b0 + k0 + 32, la + nxt * 8192 + 4096);
            GLL(b0 + 64 * K + k0 + 32, la + nxt * 8192 + 6144);
        }
        const unsigned short* As = &smem[cur * 8192];
        const unsigned short* Bs = As + 4096;
        short8 af[4], bfm[4];
        #pragma unroll
        for (int i = 0; i < 4; ++i)
            af[i] = *(const short8*)(&As[(wr * 64 + i * 16 + lcol) * 32 + quad * 8]);
        #pragma unroll
        for (int j = 0; j < 4; ++j)
            bfm[j] = *(const short8*)(&Bs[(wc * 64 + j * 16 + lcol) * 32 + quad * 8]);
        #pragma unroll
        for (int i = 0; i < 4; ++i)
            #pragma unroll
            for (int j = 0; j < 4; ++j)
                acc[i][j] = __builtin_amdgcn_mfma_f32_16x16x32_bf16(af[i], bfm[j], acc[i][j], 0, 0, 0);
    }

    #pragma unroll
    for (int i = 0; i < 4; ++i) {
        int m = m0 + wr * 64 + i * 16 + quad * 4;
        #pragma unroll
        for (int j = 0; j < 4; ++j) {
            int n = n0 + wc * 64 + j * 16 + lcol;
            float bv = bias[n];
            #pragma unroll
            for (int r = 0; r < 4; ++r)
                Cout[(size_t)(m + r) * EMB + n] = acc[i][j][r] + bv;
        }
    }
}

// ---------------------------------------------------------------------------
extern "C" void kernel_launch(void* const* d_in, const int* in_sizes, int n_in,
                              void* d_out, int out_size, void* d_ws, size_t ws_size,
                              hipStream_t stream) {
    (void)in_sizes; (void)n_in; (void)out_size; (void)ws_size;
    char* ws = (char*)d_ws;
    const size_t OFF_X     = 0;                                      // 8 MB
    const size_t OFF_WQKVT = OFF_X     + (size_t)M_ROWS * EMB * 2;   // 6 MB
    const size_t OFF_WOT   = OFF_WQKVT + (size_t)N_QKV * EMB * 2;    // 2 MB
    const size_t OFF_Q     = OFF_WOT   + (size_t)EMB * EMB * 2;      // 8 MB
    const size_t OFF_K     = OFF_Q     + (size_t)M_ROWS * EMB * 2;   // 8 MB
    const size_t OFF_V     = OFF_K     + (size_t)M_ROWS * EMB * 2;   // 8 MB
    const size_t OFF_ATTN  = OFF_V     + (size_t)M_ROWS * EMB * 2;   // 8 MB
    const size_t OFF_PART  = OFF_ATTN  + (size_t)M_ROWS * EMB * 2;   // ~8.7 MB

    const float* x    = (const float*)d_in[0];
    const float* Wqkv = (const float*)d_in[1];
    const float* bqkv = (const float*)d_in[2];
    const float* Wo   = (const float*)d_in[3];
    const float* bo   = (const float*)d_in[4];

    unsigned short* x_bf  = (unsigned short*)(ws + OFF_X);
    unsigned short* wqkvT = (unsigned short*)(ws + OFF_WQKVT);
    unsigned short* woT   = (unsigned short*)(ws + OFF_WOT);
    unsigned short* qb    = (unsigned short*)(ws + OFF_Q);
    unsigned short* kb    = (unsigned short*)(ws + OFF_K);
    unsigned short* vb    = (unsigned short*)(ws + OFF_V);    // [B,H,D,S]
    unsigned short* attn  = (unsigned short*)(ws + OFF_ATTN);
    unsigned char*  part  = (unsigned char*)(ws + OFF_PART);

    prep<<<dim3(96, 32, 3), dim3(32, 8), 0, stream>>>(x, Wqkv, Wo, x_bf, wqkvT, woT);

    qkv_gemm<<<dim3(N_QKV / 128, M_ROWS / 128), 256, 0, stream>>>(x_bf, wqkvT, bqkv, qb, kb, vb);
    attn_partial<<<dim3(48, NB * NH), 256, 0, stream>>>(qb, kb, vb, attn, part);
    attn_combine<<<dim3(16, NB * NH), 256, 0, stream>>>(part, attn);
    oproj_gemm<<<dim3(EMB / 128, M_ROWS / 128), 256, 0, stream>>>(attn, woT, bo, (float*)d_out);
}

// Round 12
// 199.514 us; speedup vs baseline: 1.4692x; 1.0652x over previous
//
#include <hip/hip_runtime.h>

// ---------------------------------------------------------------------------
// MultiHeadAttention: B=2, S=2048, E=1024, H=16, D=64, causal. fp32 I/O.
// R11b: attn computes S^T = K*Q^T so P^T exits QK in exactly the B-operand
// fragment layout of mfma_16x16x16 -> PV feeds straight from registers.
// Ps LDS buffer + round trip deleted (LDS 40.5->32KB). l per-query in every
// lane (no shuffles); packed 8B output stores. GEMMs/prep unchanged from R10.
// (R11 failed host-pass compile: mfma builtin must be guarded with
//  __HIP_DEVICE_COMPILE__ -- host pass parses device code too.)
// ---------------------------------------------------------------------------

typedef __attribute__((ext_vector_type(8))) short short8;
typedef __attribute__((ext_vector_type(4))) short short4v;
typedef __attribute__((ext_vector_type(4))) float floatx4;

#define NB 2
#define SEQ 2048
#define EMB 1024
#define NH 16
#define HD 64
#define M_ROWS (NB * SEQ)        // 4096
#define N_QKV (3 * EMB)          // 3072
#define SLOT_B 8448              // bytes: 64x64 bf16 O (8192) + 64 fp32 l (256)

#define GLL(g, l) __builtin_amdgcn_global_load_lds( \
    (const __attribute__((address_space(1))) void*)(g), \
    (__attribute__((address_space(3))) void*)(l), 16, 0, 0)

#if defined(__HIP_DEVICE_COMPILE__)
#define MFMA16K16(A, B, C) __builtin_amdgcn_mfma_f32_16x16x16bf16_1k(A, B, C, 0, 0, 0)
#else
#define MFMA16K16(A, B, C) (C)   // host pass parses but never executes this
#endif

static __device__ __forceinline__ unsigned short f2bf(float f) {
    union { float f; unsigned int u; } v; v.f = f;
    unsigned int r = v.u + 0x7FFFu + ((v.u >> 16) & 1u);
    return (unsigned short)(r >> 16);
}
static __device__ __forceinline__ float bf2f(unsigned short h) {
    union { unsigned int u; float f; } v; v.u = ((unsigned int)h) << 16;
    return v.f;
}

// Fused prep: z=0 transpose W_qkv, z=1 transpose W_o, z=2 convert x -> bf16.
__global__ void prep(const float* __restrict__ x,
                     const float* __restrict__ Wqkv, const float* __restrict__ Wo,
                     unsigned short* __restrict__ x_bf,
                     unsigned short* __restrict__ wqkvT, unsigned short* __restrict__ woT) {
    __shared__ unsigned short tile[32][33];
    int z = blockIdx.z;
    int tx = threadIdx.x, ty = threadIdx.y;
    if (z == 2) {
        int id = ((int)blockIdx.y * 96 + (int)blockIdx.x) * 256 + ty * 32 + tx;
        const int n4 = M_ROWS * EMB / 4;
        for (int i = id; i < n4; i += 96 * 32 * 256) {
            float4 v = ((const float4*)x)[i];
            unsigned long long p = (unsigned long long)f2bf(v.x)
                | ((unsigned long long)f2bf(v.y) << 16)
                | ((unsigned long long)f2bf(v.z) << 32)
                | ((unsigned long long)f2bf(v.w) << 48);
            ((unsigned long long*)x_bf)[i] = p;
        }
        return;
    }
    int C = z ? EMB : N_QKV;
    if ((int)blockIdx.x * 32 >= C) return;
    const float* in = z ? Wo : Wqkv;
    unsigned short* out = z ? woT : wqkvT;
    const int R = EMB;
    int c0 = blockIdx.x * 32, r0 = blockIdx.y * 32;
    #pragma unroll
    for (int j = 0; j < 4; ++j)
        tile[ty + j * 8][tx] = f2bf(in[(size_t)(r0 + ty + j * 8) * C + c0 + tx]);
    __syncthreads();
    #pragma unroll
    for (int j = 0; j < 4; ++j)
        out[(size_t)(c0 + ty + j * 8) * R + r0 + tx] = tile[tx][ty + j * 8];
}

// ---------------------------------------------------------------------------
// QKV GEMM: single-barrier dbuf GLL K-loop + LDS-roundtrip coalesced epilogue.
// Q,K -> [B,H,S,D]; V -> [B,H,D,S].
// ---------------------------------------------------------------------------
#define CTS 130   // C-tile LDS stride (shorts), pad 2

__global__ __launch_bounds__(256) void qkv_gemm(
    const unsigned short* __restrict__ A,    // x_bf [4096][1024]
    const unsigned short* __restrict__ Bt,   // W_qkv^T [3072][1024] bf16
    const float* __restrict__ bias,          // [3072] fp32
    unsigned short* __restrict__ qb, unsigned short* __restrict__ kb,
    unsigned short* __restrict__ vb)         // vb: [B,H,D,S]
{
    const int K = EMB;
    __shared__ __align__(16) unsigned short smem[128 * CTS];

    int t = threadIdx.x;
    int m0 = blockIdx.y * 128;
    int n0 = blockIdx.x * 128;
    int w = t >> 6, lane = t & 63, quad = lane >> 4, lcol = lane & 15;
    int wr = w >> 1, wc = w & 1;

    floatx4 zero = {0.f, 0.f, 0.f, 0.f};
    floatx4 acc[4][4];
    #pragma unroll
    for (int i = 0; i < 4; ++i)
        #pragma unroll
        for (int j = 0; j < 4; ++j) acc[i][j] = zero;

    const unsigned short* a0 = A  + (size_t)(m0 + (t >> 2)) * K + ((t & 3) << 3);
    const unsigned short* b0 = Bt + (size_t)(n0 + (t >> 2)) * K + ((t & 3) << 3);
    unsigned short* la = &smem[t << 3];          // + buf*8192 ; Bs at +4096

    GLL(a0, la);
    GLL(a0 + 64 * K, la + 2048);
    GLL(b0, la + 4096);
    GLL(b0 + 64 * K, la + 6144);

    for (int k0 = 0; k0 < K; k0 += 32) {
        int cur = (k0 >> 5) & 1, nxt = cur ^ 1;
        __syncthreads();                         // drains cur's staging loads
        if (k0 + 32 < K) {                       // prefetch nxt AFTER barrier
            GLL(a0 + k0 + 32, la + nxt * 8192);
            GLL(a0 + 64 * K + k0 + 32, la + nxt * 8192 + 2048);
            GLL(b0 + k0 + 32, la + nxt * 8192 + 4096);
            GLL(b0 + 64 * K + k0 + 32, la + nxt * 8192 + 6144);
        }
        const unsigned short* As = &smem[cur * 8192];
        const unsigned short* Bs = As + 4096;
        short8 af[4], bfm[4];
        #pragma unroll
        for (int i = 0; i < 4; ++i)
            af[i] = *(const short8*)(&As[(wr * 64 + i * 16 + lcol) * 32 + quad * 8]);
        #pragma unroll
        for (int j = 0; j < 4; ++j)
            bfm[j] = *(const short8*)(&Bs[(wc * 64 + j * 16 + lcol) * 32 + quad * 8]);
        #pragma unroll
        for (int i = 0; i < 4; ++i)
            #pragma unroll
            for (int j = 0; j < 4; ++j)
                acc[i][j] = __builtin_amdgcn_mfma_f32_16x16x32_bf16(af[i], bfm[j], acc[i][j], 0, 0, 0);
    }

    // ---- epilogue: bias + bf16 into LDS C-tile, then coalesced streams ----
    bool isV = (n0 >= 2 * EMB);
    __syncthreads();
    #pragma unroll
    for (int i = 0; i < 4; ++i) {
        int row0 = wr * 64 + i * 16 + quad * 4;
        #pragma unroll
        for (int j = 0; j < 4; ++j) {
            int col = wc * 64 + j * 16 + lcol;
            float bv = bias[n0 + col];
            #pragma unroll
            for (int r = 0; r < 4; ++r) {
                unsigned short hv = f2bf(acc[i][j][r] + bv);
                if (isV) smem[col * CTS + row0 + r] = hv;   // [feature][token]
                else     smem[(row0 + r) * CTS + col] = hv; // [token][feature]
            }
        }
    }
    __syncthreads();

    int b = m0 >> 11, s0 = m0 & 2047;
    int hbase = (n0 & 1023) >> 6;
    if (!isV) {
        unsigned short* dst = (n0 >= EMB) ? kb : qb;
        #pragma unroll
        for (int it = 0; it < 8; ++it) {
            int job = it * 32 + (t >> 3);
            int tok = job & 127, hh = job >> 7;
            int chunk = t & 7;
            short8 vv = *(const short8*)(&smem[tok * CTS + hh * 64 + chunk * 8]);
            size_t g = ((size_t)((b * NH + hbase + hh) * SEQ + s0 + tok)) * HD + chunk * 8;
            *(short8*)(&dst[g]) = vv;
        }
    } else {
        #pragma unroll
        for (int it = 0; it < 8; ++it) {
            int job = it * 32 + (t >> 3);
            int f = job & 127, half = job >> 7;
            int chunk = (t & 7) + half * 8;
            short8 vv = *(const short8*)(&smem[f * CTS + chunk * 8]);
            int h = hbase + (f >> 6), d = f & 63;
            size_t g = ((size_t)((b * NH + h) * HD + d)) * SEQ + s0 + chunk * 8;
            *(short8*)(&vb[g]) = vv;
        }
    }
}

// ---------------------------------------------------------------------------
// Split-K flash attention, causal, fixed softmax base. Block (u, bh):
//   u<16:  qt=u, keys [0, qt+1)           -> final bf16 write
//   u>=16: qt=16+(u-16)/2, c=(u-16)&1, keys c0=[0,16) c1=[16,qt+1)
// S^T = K*Q^T (C-layout == 16x16x16 B-frag layout) -> PV direct from regs.
// ---------------------------------------------------------------------------
__global__ __launch_bounds__(256) void attn_partial(
    const unsigned short* __restrict__ Q,   // [B*H][S][D]
    const unsigned short* __restrict__ Kk,  // [B*H][S][D]
    const unsigned short* __restrict__ Vt,  // [B*H][D][S]
    unsigned short* __restrict__ Out,       // [b][s][h*64+d]
    unsigned char* __restrict__ Part)       // partial slots (bf16 O + fp32 l)
{
    __shared__ __align__(16) unsigned short Ks[2][64 * 64];
    __shared__ __align__(16) unsigned short Vs[2][64 * 64];

    int u = blockIdx.x;              // 0..47
    int bh = blockIdx.y;
    int qt, c;
    if (u < 16) { qt = u; c = 0; }
    else { int v = u - 16; qt = 16 + (v >> 1); c = v & 1; }
    int ktBeg = c << 4;
    int ktEnd = (c == 0 && qt >= 16) ? 16 : (qt + 1);

    int q0 = qt * 64;
    int t = threadIdx.x;
    int w = t >> 6, lane = t & 63, quad = lane >> 4, lcol = lane & 15;
    const size_t hoff = (size_t)bh * SEQ * HD;
    const float SC = 0.18033688011112043f;   // (1/sqrt(64)) * log2(e)

    // Q strip (B-operand now; same addresses as before)
    const unsigned short* qp = Q + hoff + (size_t)(q0 + 16 * w + lcol) * HD + quad * 8;
    short8 aq0 = *(const short8*)qp, aq1 = *(const short8*)(qp + 32);

    int srow = t >> 3;                       // 0..31
    int ss   = (t & 7) ^ (srow & 7);
    const unsigned short* kgl = Kk + hoff + (size_t)srow * HD + ss * 8;
    const unsigned short* vgl = Vt + hoff + (size_t)srow * SEQ + ss * 8;
    unsigned short* kld = &Ks[0][t * 8];
    unsigned short* vld = &Vs[0][t * 8];

    floatx4 zero = {0.f, 0.f, 0.f, 0.f};
    floatx4 O[4];                            // O^T: row=d(quad*4+r in td*16), col=query lcol
    floatx4 lacc = zero;                     // all rows = l[query lcol]
    #pragma unroll
    for (int d = 0; d < 4; ++d) O[d] = zero;

    short4v ones4;
    #pragma unroll
    for (int j = 0; j < 4; ++j) ones4[j] = (short)0x3F80;  // bf16 1.0

    {   // prologue: stage tile ktBeg into buf 0 (ktBeg is even)
        int k0 = ktBeg * 64;
        GLL(kgl + (size_t)k0 * HD, kld);
        GLL(kgl + (size_t)(k0 + 32) * HD, kld + 2048);
        GLL(vgl + k0, vld);
        GLL(vgl + (size_t)32 * SEQ + k0, vld + 2048);
    }

    int sx0 = (quad ^ (lcol & 7)) << 3;
    int sx1 = sx0 ^ 32;

    for (int kt = ktBeg; kt < ktEnd; ++kt) {
        int cur = kt & 1, nxt = cur ^ 1;
        __syncthreads();                     // drains tile-kt staging loads
        if (kt + 1 < ktEnd) {
            int k0 = (kt + 1) * 64;
            GLL(kgl + (size_t)k0 * HD, kld + nxt * 4096);
            GLL(kgl + (size_t)(k0 + 32) * HD, kld + nxt * 4096 + 2048);
            GLL(vgl + k0, vld + nxt * 4096);
            GLL(vgl + (size_t)32 * SEQ + k0, vld + nxt * 4096 + 2048);
        }

        const unsigned short* ksr = &Ks[cur][0];
        const unsigned short* vsr = &Vs[cur][0];
        short8 bk0[4], bk1[4];
        #pragma unroll
        for (int tc = 0; tc < 4; ++tc) {
            int rb = (tc * 16 + lcol) << 6;
            bk0[tc] = *(const short8*)(ksr + rb + sx0);
            bk1[tc] = *(const short8*)(ksr + rb + sx1);
        }

        // S^T = K * Q^T  (A = K tile rows=keys, B = Q strip cols=queries)
        floatx4 sacc[4];
        #pragma unroll
        for (int tc = 0; tc < 4; ++tc) {
            sacc[tc] = __builtin_amdgcn_mfma_f32_16x16x32_bf16(bk0[tc], aq0, zero, 0, 0, 0);
            sacc[tc] = __builtin_amdgcn_mfma_f32_16x16x32_bf16(bk1[tc], aq1, sacc[tc], 0, 0, 0);
        }

        // P^T = exp2(S^T * SC), packed bf16 -> directly the 16x16x16 B-frag
        short4v pk[4];
        if (kt == qt) {                       // diagonal tile (once per block)
            int qrow = q0 + 16 * w + lcol;
            int kbase = kt * 64 + quad * 4;
            #pragma unroll
            for (int tc = 0; tc < 4; ++tc) {
                #pragma unroll
                for (int r = 0; r < 4; ++r) {
                    float p = __builtin_amdgcn_exp2f(sacc[tc][r] * SC);
                    if (kbase + tc * 16 + r > qrow) p = 0.f;
                    pk[tc][r] = (short)f2bf(p);
                }
            }
        } else {
            #pragma unroll
            for (int tc = 0; tc < 4; ++tc) {
                #pragma unroll
                for (int r = 0; r < 4; ++r)
                    pk[tc][r] = (short)f2bf(__builtin_amdgcn_exp2f(sacc[tc][r] * SC));
            }
        }

        // O^T += V^T * P^T   (A = V^T frag b64 from swizzled Vs, B = pk regs)
        #pragma unroll
        for (int td = 0; td < 4; ++td) {
            short4v va[4];
            #pragma unroll
            for (int tc = 0; tc < 4; ++tc) {
                int seg = ((tc << 1) + (quad >> 1)) ^ (lcol & 7);
                va[tc] = *(const short4v*)(vsr + ((td * 16 + lcol) << 6) + (seg << 3) + ((quad & 1) << 2));
            }
            #pragma unroll
            for (int tc = 0; tc < 4; ++tc)
                O[td] = MFMA16K16(va[tc], pk[tc], O[td]);
        }
        // l[q] += sum_key P^T[key][q]  (every lane gets its query's l)
        #pragma unroll
        for (int tc = 0; tc < 4; ++tc)
            lacc = MFMA16K16(ones4, pk[tc], lacc);
    }

    int qrow = q0 + 16 * w + lcol;           // this lane's query row
    if (qt < 16) {
        int b = bh >> 4, h = bh & 15;
        float inv = 1.0f / lacc[0];
        size_t obase = ((size_t)b * SEQ + qrow) * EMB + (size_t)h * HD + quad * 4;
        #pragma unroll
        for (int td = 0; td < 4; ++td) {
            short4v ov;
            #pragma unroll
            for (int r = 0; r < 4; ++r) ov[r] = (short)f2bf(O[td][r] * inv);
            *(short4v*)(&Out[obase + td * 16]) = ov;
        }
    } else {
        unsigned char* sp = Part + ((size_t)(bh * 16 + (qt - 16)) * 2 + c) * SLOT_B;
        unsigned short* sO = (unsigned short*)sp;   // [q_local][d]
        float* sL = (float*)(sp + 8192);
        int ql = 16 * w + lcol;
        #pragma unroll
        for (int td = 0; td < 4; ++td) {
            short4v ov;
            #pragma unroll
            for (int r = 0; r < 4; ++r) ov[r] = (short)f2bf(O[td][r]);
            *(short4v*)(&sO[ql * 64 + td * 16 + quad * 4]) = ov;
        }
        if (quad == 0) sL[ql] = lacc[0];
    }
}

// merge the 2 partials per (bh, qt>=16) and write bf16 attn rows
__global__ __launch_bounds__(256) void attn_combine(
    const unsigned char* __restrict__ Part, unsigned short* __restrict__ Out)
{
    int qh = blockIdx.x;             // 0..15
    int bh = blockIdx.y;
    int qt = 16 + qh;
    const unsigned char* s0 = Part + ((size_t)(bh * 16 + qh) * 2) * SLOT_B;
    const unsigned char* s1 = s0 + SLOT_B;
    const unsigned short* O0 = (const unsigned short*)s0;
    const unsigned short* O1 = (const unsigned short*)s1;
    const float* L0 = (const float*)(s0 + 8192);
    const float* L1 = (const float*)(s1 + 8192);
    int b = bh >> 4, h = bh & 15;
    size_t obase = ((size_t)b * SEQ + qt * 64) * EMB + (size_t)h * HD;
    int t = threadIdx.x;
    #pragma unroll
    for (int it = 0; it < 16; ++it) {
        int idx = it * 256 + t;
        int row = idx >> 6, col = idx & 63;
        float lv = L0[row] + L1[row];
        float v = (bf2f(O0[idx]) + bf2f(O1[idx])) / lv;
        Out[obase + (size_t)row * EMB + col] = f2bf(v);
    }
}

// ---------------------------------------------------------------------------
// Output projection: single-barrier dbuf GLL K-loop. fp32 bias, fp32 out.
// ---------------------------------------------------------------------------
__global__ __launch_bounds__(256) void oproj_gemm(
    const unsigned short* __restrict__ A,    // [4096][1024] bf16
    const unsigned short* __restrict__ Bt,   // W_o^T [1024][1024] bf16
    const float* __restrict__ bias,          // [1024] fp32
    float* __restrict__ Cout)                // [4096][1024] fp32
{
    const int K = EMB;
    __shared__ __align__(16) unsigned short smem[2 * 8192];
    int t = threadIdx.x;
    int m0 = blockIdx.y * 128;
    int n0 = blockIdx.x * 128;
    int w = t >> 6, lane = t & 63, quad = lane >> 4, lcol = lane & 15;
    int wr = w >> 1, wc = w & 1;

    floatx4 zero = {0.f, 0.f, 0.f, 0.f};
    floatx4 acc[4][4];
    #pragma unroll
    for (int i = 0; i < 4; ++i)
        #pragma unroll
        for (int j = 0; j < 4; ++j) acc[i][j] = zero;

    const unsigned short* a0 = A  + (size_t)(m0 + (t >> 2)) * K + ((t & 3) << 3);
    const unsigned short* b0 = Bt + (size_t)(n0 + (t >> 2)) * K + ((t & 3) << 3);
    unsigned short* la = &smem[t << 3];

    GLL(a0, la);
    GLL(a0 + 64 * K, la + 2048);
    GLL(b0, la + 4096);
    GLL(b0 + 64 * K, la + 6144);

    for (int k0 = 0; k0 < K; k0 += 32) {
        int cur = (k0 >> 5) & 1, nxt = cur ^ 1;
        __syncthreads();
        if (k0 + 32 < K) {
            GLL(a0 + k0 + 32, la + nxt * 8192);
            GLL(a0 + 64 * K + k0 + 32, la + nxt * 8192 + 2048);
            GLL(b0 + k0 + 32, la + nxt * 8192 + 4096);
            GLL(b0 + 64 * K + k0 + 32, la + nxt * 8192 + 6144);
        }
        const unsigned short* As = &smem[cur * 8192];
        const unsigned short* Bs = As + 4096;
        short8 af[4], bfm[4];
        #pragma unroll
        for (int i = 0; i < 4; ++i)
            af[i] = *(const short8*)(&As[(wr * 64 + i * 16 + lcol) * 32 + quad * 8]);
        #pragma unroll
        for (int j = 0; j < 4; ++j)
            bfm[j] = *(const short8*)(&Bs[(wc * 64 + j * 16 + lcol) * 32 + quad * 8]);
        #pragma unroll
        for (int i = 0; i < 4; ++i)
            #pragma unroll
            for (int j = 0; j < 4; ++j)
                acc[i][j] = __builtin_amdgcn_mfma_f32_16x16x32_bf16(af[i], bfm[j], acc[i][j], 0, 0, 0);
    }

    #pragma unroll
    for (int i = 0; i < 4; ++i) {
        int m = m0 + wr * 64 + i * 16 + quad * 4;
        #pragma unroll
        for (int j = 0; j < 4; ++j) {
            int n = n0 + wc * 64 + j * 16 + lcol;
            float bv = bias[n];
            #pragma unroll
            for (int r = 0; r < 4; ++r)
                Cout[(size_t)(m + r) * EMB + n] = acc[i][j][r] + bv;
        }
    }
}

// ---------------------------------------------------------------------------
extern "C" void kernel_launch(void* const* d_in, const int* in_sizes, int n_in,
                              void* d_out, int out_size, void* d_ws, size_t ws_size,
                              hipStream_t stream) {
    (void)in_sizes; (void)n_in; (void)out_size; (void)ws_size;
    char* ws = (char*)d_ws;
    const size_t OFF_X     = 0;                                      // 8 MB
    const size_t OFF_WQKVT = OFF_X     + (size_t)M_ROWS * EMB * 2;   // 6 MB
    const size_t OFF_WOT   = OFF_WQKVT + (size_t)N_QKV * EMB * 2;    // 2 MB
    const size_t OFF_Q     = OFF_WOT   + (size_t)EMB * EMB * 2;      // 8 MB
    const size_t OFF_K     = OFF_Q     + (size_t)M_ROWS * EMB * 2;   // 8 MB
    const size_t OFF_V     = OFF_K     + (size_t)M_ROWS * EMB * 2;   // 8 MB
    const size_t OFF_ATTN  = OFF_V     + (size_t)M_ROWS * EMB * 2;   // 8 MB
    const size_t OFF_PART  = OFF_ATTN  + (size_t)M_ROWS * EMB * 2;   // ~8.7 MB

    const float* x    = (const float*)d_in[0];
    const float* Wqkv = (const float*)d_in[1];
    const float* bqkv = (const float*)d_in[2];
    const float* Wo   = (const float*)d_in[3];
    const float* bo   = (const float*)d_in[4];

    unsigned short* x_bf  = (unsigned short*)(ws + OFF_X);
    unsigned short* wqkvT = (unsigned short*)(ws + OFF_WQKVT);
    unsigned short* woT   = (unsigned short*)(ws + OFF_WOT);
    unsigned short* qb    = (unsigned short*)(ws + OFF_Q);
    unsigned short* kb    = (unsigned short*)(ws + OFF_K);
    unsigned short* vb    = (unsigned short*)(ws + OFF_V);    // [B,H,D,S]
    unsigned short* attn  = (unsigned short*)(ws + OFF_ATTN);
    unsigned char*  part  = (unsigned char*)(ws + OFF_PART);

    prep<<<dim3(96, 32, 3), dim3(32, 8), 0, stream>>>(x, Wqkv, Wo, x_bf, wqkvT, woT);

    qkv_gemm<<<dim3(N_QKV / 128, M_ROWS / 128), 256, 0, stream>>>(x_bf, wqkvT, bqkv, qb, kb, vb);
    attn_partial<<<dim3(48, NB * NH), 256, 0, stream>>>(qb, kb, vb, attn, part);
    attn_combine<<<dim3(16, NB * NH), 256, 0, stream>>>(part, attn);
    oproj_gemm<<<dim3(EMB / 128, M_ROWS / 128), 256, 0, stream>>>(attn, woT, bo, (float*)d_out);
}